// Round 1
// baseline (8723.189 us; speedup 1.0000x reference)
//
#include <hip/hip_runtime.h>

#define DEV static __device__ __forceinline__

typedef short  s16x8 __attribute__((ext_vector_type(8)));
typedef float  f32x4 __attribute__((ext_vector_type(4)));
typedef _Float16 h2f __attribute__((ext_vector_type(2)));

constexpr int S = 400, B = 32, T = 32, V = 50000, OOV = 50, E = 128, H = 256;
constexpr int H4 = 1024, VO = V + OOV, SB = S * B;

DEV ushort f2bf(float x) {
    union { float f; unsigned u; } a; a.f = x;
    unsigned r = (a.u + 0x7fffu + ((a.u >> 16) & 1u)) >> 16;
    return (ushort)r;
}
DEV float bf2f(unsigned b) {
    union { unsigned u; float f; } a; a.u = b << 16; return a.f;
}
DEV float sigmoidf_(float x) { return 1.0f / (1.0f + __expf(-x)); }
DEV float tanhf_(float x) { float e = __expf(2.0f * x); return 1.0f - 2.0f / (e + 1.0f); }
DEV h2f asH2(unsigned u) { union { unsigned u; h2f h; } x; x.u = u; return x.h; }

#if __has_builtin(__builtin_amdgcn_fdot2)
DEV float dot2(h2f a, h2f b, float c) { return __builtin_amdgcn_fdot2(a, b, c, false); }
#else
DEV float dot2(h2f a, h2f b, float c) { return c + (float)a.x * (float)b.x + (float)a.y * (float)b.y; }
#endif

// ---------------- workspace layout ----------------
constexpr size_t SZ_EMB2D  = (size_t)SB * E * 2;        // bf16
constexpr size_t SZ_WIHCAT = (size_t)2048 * 128 * 2;    // bf16
constexpr size_t SZ_BIASX  = 2048 * 4;
constexpr size_t SZ_WFEAT  = (size_t)512 * 512 * 2;     // bf16
constexpr size_t SZ_WO2    = (size_t)V * H * 2;         // bf16
constexpr size_t SZ_WO1    = (size_t)256 * 1024 * 2;    // bf16
constexpr size_t SZ_WHHPK  = (size_t)2 * 128 * 256 * 16; // f16 packed, uint4 per (kp,j)
constexpr size_t SZ_WC     = (size_t)1024 * 640 * 4;
constexpr size_t SZ_BC     = 1024 * 4;
constexpr size_t SZ_UPG    = 640 * 4;
constexpr size_t SZ_CPG    = 256;
constexpr size_t SZ_XPROJ  = (size_t)SB * 2048 * 2;     // f16
constexpr size_t SZ_ENCOUT = (size_t)SB * 512 * 2;      // bf16
constexpr size_t SZ_ENCFEAT= (size_t)SB * 512 * 2;      // f16
constexpr size_t SZ_HFIN   = (size_t)2 * B * H * 4;
constexpr size_t SZ_HDEC   = (size_t)2 * B * H * 4;
constexpr size_t SZ_CTX    = (size_t)B * 512 * 4;
constexpr size_t SZ_DAF    = (size_t)B * 512 * 4;
constexpr size_t SZ_EXPS   = (size_t)SB * 4;
constexpr size_t SZ_PGEN   = 256;
constexpr size_t SZ_HIDBF  = (size_t)B * 256 * 2;
constexpr size_t SZ_SUMV   = 256;

constexpr size_t OFF_EMB2D  = 0;
constexpr size_t OFF_WIHCAT = OFF_EMB2D  + SZ_EMB2D;
constexpr size_t OFF_BIASX  = OFF_WIHCAT + SZ_WIHCAT;
constexpr size_t OFF_WFEAT  = OFF_BIASX  + SZ_BIASX;
constexpr size_t OFF_WO2    = OFF_WFEAT  + SZ_WFEAT;
constexpr size_t OFF_WO1    = OFF_WO2    + SZ_WO2;
constexpr size_t OFF_WHHPK  = OFF_WO1    + SZ_WO1;
constexpr size_t OFF_WC     = OFF_WHHPK  + SZ_WHHPK;
constexpr size_t OFF_BC     = OFF_WC     + SZ_WC;
constexpr size_t OFF_UPG    = OFF_BC     + SZ_BC;
constexpr size_t OFF_CPG    = OFF_UPG    + SZ_UPG;
constexpr size_t OFF_XPROJ  = OFF_CPG    + SZ_CPG;
constexpr size_t OFF_ENCOUT = OFF_XPROJ  + SZ_XPROJ;
constexpr size_t OFF_ENCFEAT= OFF_ENCOUT + SZ_ENCOUT;
constexpr size_t OFF_HFIN   = OFF_ENCFEAT+ SZ_ENCFEAT;
constexpr size_t OFF_CFIN   = OFF_HFIN   + SZ_HFIN;
constexpr size_t OFF_HDEC   = OFF_CFIN   + SZ_HFIN;
constexpr size_t OFF_CDEC   = OFF_HDEC   + SZ_HDEC;
constexpr size_t OFF_CTX    = OFF_CDEC   + SZ_HDEC;
constexpr size_t OFF_DAF    = OFF_CTX    + SZ_CTX;
constexpr size_t OFF_EXPS   = OFF_DAF    + SZ_DAF;
constexpr size_t OFF_PGEN   = OFF_EXPS   + SZ_EXPS;
constexpr size_t OFF_HIDBF  = OFF_PGEN   + SZ_PGEN;
constexpr size_t OFF_SUMV   = OFF_HIDBF  + SZ_HIDBF;
constexpr size_t OFF_PBUF   = OFF_XPROJ;  // alias: xproj dead after encoder

// ---------------- prep: weight conversions / precomputes ----------------
constexpr long N1 = 2048L*128;   // wihcat
constexpr long N2 = 2048;        // biasx
constexpr long N3 = 512L*512;    // wfeat
constexpr long N4 = (long)V*H;   // wo2
constexpr long N5 = 256L*1024;   // wo1
constexpr long N6 = 2L*128*256*4;// whhpk dwords
constexpr long N7 = 1024L*640;   // wc
constexpr long N8 = 640;         // upg
constexpr long N9 = 1;           // cpg
constexpr long N10 = 1024;       // bc
constexpr long N11 = (long)SB*E; // emb2d
constexpr long PREP_TOTAL = N1+N2+N3+N4+N5+N6+N7+N8+N9+N10+N11;

__global__ __launch_bounds__(256)
void prep_kernel(const float* __restrict__ Wih_f, const float* __restrict__ Wih_b,
                 const float* __restrict__ bih_f, const float* __restrict__ bhh_f,
                 const float* __restrict__ bih_b, const float* __restrict__ bhh_b,
                 const float* __restrict__ W_feat, const float* __restrict__ W_o2,
                 const float* __restrict__ W_o1, const float* __restrict__ Whh_f,
                 const float* __restrict__ Whh_b, const float* __restrict__ dWih,
                 const float* __restrict__ W_ctx, const float* __restrict__ W_pg,
                 const float* __restrict__ b_pg, const float* __restrict__ b_ctx,
                 const float* __restrict__ dbih, const float* __restrict__ dbhh,
                 const float* __restrict__ emb, const int* __restrict__ inputs,
                 ushort* __restrict__ emb2d, ushort* __restrict__ wihcat,
                 float* __restrict__ biasx, ushort* __restrict__ wfeatbf,
                 ushort* __restrict__ wo2bf, ushort* __restrict__ wo1bf,
                 unsigned* __restrict__ whhpk, float* __restrict__ wcm,
                 float* __restrict__ upg, float* __restrict__ cpgp, float* __restrict__ bcv)
{
    long id = (long)blockIdx.x * 256 + threadIdx.x;
    if (id < N1) { int r = id >> 7, e = id & 127;
        float v = (r < 1024) ? Wih_f[r*128+e] : Wih_b[(r-1024)*128+e];
        wihcat[id] = f2bf(v); return; }
    id -= N1;
    if (id < N2) { biasx[id] = (id < 1024) ? bih_f[id]+bhh_f[id] : bih_b[id-1024]+bhh_b[id-1024]; return; }
    id -= N2;
    if (id < N3) { wfeatbf[id] = f2bf(W_feat[id]); return; }
    id -= N3;
    if (id < N4) { wo2bf[id] = f2bf(W_o2[id]); return; }
    id -= N4;
    if (id < N5) { wo1bf[id] = f2bf(W_o1[id]); return; }
    id -= N5;
    if (id < N6) {
        int g = id & 3; long r = id >> 2; int jj = r & 255; r >>= 8; int kp = r & 127; int dir = r >> 7;
        const float* W = dir ? Whh_b : Whh_f;
        int row = g*256 + jj;
        h2f hv; hv.x = (_Float16)W[row*256 + 2*kp]; hv.y = (_Float16)W[row*256 + 2*kp + 1];
        whhpk[id] = __builtin_bit_cast(unsigned, hv); return; }
    id -= N6;
    if (id < N7) { int g = id / 640, u = id % 640;
        float acc = 0.f;
        for (int e = 0; e < 128; ++e) acc += dWih[g*128+e] * W_ctx[e*640+u];
        wcm[id] = acc; return; }
    id -= N7;
    if (id < N8) { float acc = 0.f;
        for (int e = 0; e < 128; ++e) acc += W_pg[1024+e] * W_ctx[e*640+(int)id];
        upg[id] = acc; return; }
    id -= N8;
    if (id < N9) { float acc = b_pg[0];
        for (int e = 0; e < 128; ++e) acc += W_pg[1024+e] * b_ctx[e];
        cpgp[0] = acc; return; }
    id -= N9;
    if (id < N10) { float acc = dbih[id] + dbhh[id];
        for (int e = 0; e < 128; ++e) acc += dWih[id*128+e] * b_ctx[e];
        bcv[id] = acc; return; }
    id -= N10;
    if (id < N11) { long sb = id >> 7; int e = id & 127;
        emb2d[id] = f2bf(emb[(size_t)inputs[sb]*128 + e]); return; }
}

// ---------------- generic bf16 MFMA GEMM: C = A(MxK) * B(NxK)^T (+bias) ----------------
// MODE: 0 = f32 store, 1 = f16 store, 2 = f32 exp(store)
template<int BM, int BN, int MODE, bool BIAS, bool SWZ>
__global__ __launch_bounds__(256)
void gemm_nt(const ushort* __restrict__ A, int lda, const ushort* __restrict__ Bm, int ldb,
             void* __restrict__ Cp, int ldc, const float* __restrict__ bias,
             int M, int N, int K)
{
    constexpr int WN = BN / 32;
    __shared__ ushort sA[BM * 32];
    __shared__ ushort sB[BN * 32];
    int tid = threadIdx.x, lane = tid & 63, wid = tid >> 6;
    int wm = wid / WN, wn = wid % WN;
    int mb = blockIdx.y, nb = blockIdx.x;
    if (SWZ) {
        int n = gridDim.x, x = nb & 7, y = nb >> 3, q = n >> 3, r = n & 7;
        nb = (x < r ? x * (q + 1) : r * (q + 1) + (x - r) * q) + y;
    }
    int l15 = lane & 15, lg = lane >> 4;
    f32x4 acc[2][2] = {};
    for (int k0 = 0; k0 < K; k0 += 32) {
        for (int idx = tid; idx < BM * 4; idx += 256) {
            int r = idx >> 2, kc = (idx & 3) << 3;
            int row = mb * BM + r;
            uint4 v = make_uint4(0u, 0u, 0u, 0u);
            if (row < M) v = *(const uint4*)(A + (size_t)row * lda + k0 + kc);
            *(uint4*)(&sA[r * 32 + kc]) = v;
        }
        for (int idx = tid; idx < BN * 4; idx += 256) {
            int r = idx >> 2, kc = (idx & 3) << 3;
            int row = nb * BN + r;
            uint4 v = make_uint4(0u, 0u, 0u, 0u);
            if (row < N) v = *(const uint4*)(Bm + (size_t)row * ldb + k0 + kc);
            *(uint4*)(&sB[r * 32 + kc]) = v;
        }
        __syncthreads();
        s16x8 a0 = *(const s16x8*)(&sA[(wm * 32 + l15) * 32 + lg * 8]);
        s16x8 a1 = *(const s16x8*)(&sA[(wm * 32 + 16 + l15) * 32 + lg * 8]);
        s16x8 b0 = *(const s16x8*)(&sB[(wn * 32 + l15) * 32 + lg * 8]);
        s16x8 b1 = *(const s16x8*)(&sB[(wn * 32 + 16 + l15) * 32 + lg * 8]);
        acc[0][0] = __builtin_amdgcn_mfma_f32_16x16x32_bf16(a0, b0, acc[0][0], 0, 0, 0);
        acc[0][1] = __builtin_amdgcn_mfma_f32_16x16x32_bf16(a0, b1, acc[0][1], 0, 0, 0);
        acc[1][0] = __builtin_amdgcn_mfma_f32_16x16x32_bf16(a1, b0, acc[1][0], 0, 0, 0);
        acc[1][1] = __builtin_amdgcn_mfma_f32_16x16x32_bf16(a1, b1, acc[1][1], 0, 0, 0);
        __syncthreads();
    }
    int cb = nb * BN + wn * 32, rb = mb * BM + wm * 32;
    #pragma unroll
    for (int mf = 0; mf < 2; ++mf)
    #pragma unroll
    for (int nf = 0; nf < 2; ++nf) {
        int col = cb + nf * 16 + l15;
        float bv = 0.f;
        if (BIAS) { if (col < N) bv = bias[col]; }
        #pragma unroll
        for (int r = 0; r < 4; ++r) {
            int row = rb + mf * 16 + lg * 4 + r;
            if (row < M && col < N) {
                float v = acc[mf][nf][r] + bv;
                if (MODE == 0)      ((float*)Cp)[(size_t)row * ldc + col] = v;
                else if (MODE == 1) ((ushort*)Cp)[(size_t)row * ldc + col] = __builtin_bit_cast(ushort, (_Float16)v);
                else                ((float*)Cp)[(size_t)row * ldc + col] = __expf(v);
            }
        }
    }
}

// ---------------- encoder: 64 persistent WGs, one per (dir, batch row) ----------------
__global__ __launch_bounds__(256)
void enc_kernel(const ushort* __restrict__ xproj, const uint4* __restrict__ whhpk,
                ushort* __restrict__ encout, float* __restrict__ hfin, float* __restrict__ cfin)
{
    int b = blockIdx.x & 31, dir = blockIdx.x >> 5;
    int j = threadIdx.x;
    __shared__ __attribute__((aligned(16))) ushort hh[256];
    float h = 0.f, c = 0.f;
    hh[j] = 0;
    __syncthreads();
    const uint4* wbase = whhpk + (size_t)dir * 128 * 256;
    for (int step = 0; step < S; ++step) {
        int s = dir ? (S - 1 - step) : step;
        const ushort* xp = xproj + ((size_t)(s * B + b)) * 2048 + dir * 1024 + j;
        float a0 = (float)__builtin_bit_cast(_Float16, xp[0]);
        float a1 = (float)__builtin_bit_cast(_Float16, xp[256]);
        float a2 = (float)__builtin_bit_cast(_Float16, xp[512]);
        float a3 = (float)__builtin_bit_cast(_Float16, xp[768]);
        #pragma unroll 4
        for (int kp4 = 0; kp4 < 32; ++kp4) {
            uint4 hu = *(const uint4*)(&hh[kp4 * 8]);
            uint4 w0 = wbase[(kp4 * 4 + 0) * 256 + j];
            uint4 w1 = wbase[(kp4 * 4 + 1) * 256 + j];
            uint4 w2 = wbase[(kp4 * 4 + 2) * 256 + j];
            uint4 w3 = wbase[(kp4 * 4 + 3) * 256 + j];
            h2f h0 = asH2(hu.x), h1 = asH2(hu.y), h2_ = asH2(hu.z), h3 = asH2(hu.w);
            a0 = dot2(h0, asH2(w0.x), a0); a1 = dot2(h0, asH2(w0.y), a1);
            a2 = dot2(h0, asH2(w0.z), a2); a3 = dot2(h0, asH2(w0.w), a3);
            a0 = dot2(h1, asH2(w1.x), a0); a1 = dot2(h1, asH2(w1.y), a1);
            a2 = dot2(h1, asH2(w1.z), a2); a3 = dot2(h1, asH2(w1.w), a3);
            a0 = dot2(h2_, asH2(w2.x), a0); a1 = dot2(h2_, asH2(w2.y), a1);
            a2 = dot2(h2_, asH2(w2.z), a2); a3 = dot2(h2_, asH2(w2.w), a3);
            a0 = dot2(h3, asH2(w3.x), a0); a1 = dot2(h3, asH2(w3.y), a1);
            a2 = dot2(h3, asH2(w3.z), a2); a3 = dot2(h3, asH2(w3.w), a3);
        }
        float ig = sigmoidf_(a0), fg = sigmoidf_(a1), gg = tanhf_(a2), og = sigmoidf_(a3);
        c = fg * c + ig * gg;
        h = og * tanhf_(c);
        encout[((size_t)(s * B + b)) * 512 + dir * 256 + j] = f2bf(h);
        __syncthreads();   // all reads of old hh done
        hh[j] = __builtin_bit_cast(ushort, (_Float16)h);
        __syncthreads();
    }
    hfin[(dir * 32 + b) * 256 + j] = h;
    cfin[(dir * 32 + b) * 256 + j] = c;
}

// ---------------- decoder init: dh0/dc0 + zero ctx ----------------
__global__ __launch_bounds__(256)
void initdec_kernel(const float* __restrict__ hfin, const float* __restrict__ cfin,
                    const float* __restrict__ W_rh, const float* __restrict__ b_rh,
                    const float* __restrict__ W_rc, const float* __restrict__ b_rc,
                    float* __restrict__ hdec0, float* __restrict__ cdec0, float* __restrict__ ctx)
{
    int b = blockIdx.x, j = threadIdx.x;
    float ah = b_rh[j], ac = b_rc[j];
    const float* wh = W_rh + (size_t)j * 512;
    const float* wc = W_rc + (size_t)j * 512;
    for (int k = 0; k < 256; ++k) {
        float hf = hfin[b * 256 + k], hb = hfin[(32 + b) * 256 + k];
        ah += hf * wh[k] + hb * wh[256 + k];
        float cf = cfin[b * 256 + k], cb = cfin[(32 + b) * 256 + k];
        ac += cf * wc[k] + cb * wc[256 + k];
    }
    hdec0[b * 256 + j] = fmaxf(ah, 0.f);
    cdec0[b * 256 + j] = fmaxf(ac, 0.f);
    ctx[b * 512 + j] = 0.f;
    ctx[b * 512 + 256 + j] = 0.f;
}

// ---------------- E1: decoder LSTM (+ scatter of previous step) ----------------
__global__ __launch_bounds__(256)
void dec_lstm_kernel(const float* __restrict__ ctx, const float* __restrict__ emb,
                     const int* __restrict__ toks, const float* __restrict__ wcm,
                     const float* __restrict__ whh, const float* __restrict__ bcv,
                     const float* __restrict__ hprev, const float* __restrict__ cprev,
                     float* __restrict__ hnew, float* __restrict__ cnew,
                     int tprev, const float* __restrict__ pgen, const int* __restrict__ tex,
                     const float* __restrict__ atts_prev, float* __restrict__ outs_prev)
{
    int t = threadIdx.x;
    if (blockIdx.x >= 128) {
        if (tprev < 0) return;
        int id = (blockIdx.x - 128) * 256 + t;   // id = s*32 + b
        int b = id & 31;
        float v = (1.f - pgen[b]) * atts_prev[id];
        atomicAdd(outs_prev + (size_t)b * VO + tex[id], v);
        return;
    }
    int b = t & 31, ci = t >> 5;
    int gi = ci >> 1, jj = ci & 1;
    int j = (blockIdx.x << 1) + jj;
    int col = gi * 256 + j;
    float acc = bcv[col];
    {
        const float4* w = (const float4*)(wcm + (size_t)col * 640);
        const float4* x = (const float4*)(ctx + b * 512);
        #pragma unroll 8
        for (int u = 0; u < 128; ++u) { float4 a = w[u], q = x[u]; acc += a.x*q.x + a.y*q.y + a.z*q.z + a.w*q.w; }
        const float4* w2 = (const float4*)(wcm + (size_t)col * 640 + 512);
        const float4* x2 = (const float4*)(emb + (size_t)toks[b] * 128);
        #pragma unroll 8
        for (int u = 0; u < 32; ++u) { float4 a = w2[u], q = x2[u]; acc += a.x*q.x + a.y*q.y + a.z*q.z + a.w*q.w; }
        const float4* w3 = (const float4*)(whh + (size_t)col * 256);
        const float4* x3 = (const float4*)(hprev + b * 256);
        #pragma unroll 8
        for (int u = 0; u < 64; ++u) { float4 a = w3[u], q = x3[u]; acc += a.x*q.x + a.y*q.y + a.z*q.z + a.w*q.w; }
    }
    __shared__ float pre[256];
    pre[t] = acc;     // pre[ci*32 + b]
    __syncthreads();
    if (t < 64) {
        int b2 = t & 31, q = t >> 5;
        int j2 = (blockIdx.x << 1) + q;
        float iv = pre[(0 + q) * 32 + b2];
        float fv = pre[(2 + q) * 32 + b2];
        float gv = pre[(4 + q) * 32 + b2];
        float ov = pre[(6 + q) * 32 + b2];
        float cp = cprev[b2 * 256 + j2];
        float cn = sigmoidf_(fv) * cp + sigmoidf_(iv) * tanhf_(gv);
        float hn = sigmoidf_(ov) * tanhf_(cn);
        cnew[b2 * 256 + j2] = cn;
        hnew[b2 * 256 + j2] = hn;
    }
}

// ---------------- E2: daf = dh @ W_af^T + b_af ----------------
__global__ __launch_bounds__(256)
void dec_daf_kernel(const float* __restrict__ h, const float* __restrict__ c,
                    const float* __restrict__ W_af, const float* __restrict__ b_af,
                    float* __restrict__ daf)
{
    int t = threadIdx.x, b = t & 31, di = t >> 5;
    int d = blockIdx.x * 8 + di;
    float acc = b_af[d];
    const float4* w  = (const float4*)(W_af + (size_t)d * 512);
    const float4* xh = (const float4*)(h + b * 256);
    const float4* xc = (const float4*)(c + b * 256);
    #pragma unroll 8
    for (int u = 0; u < 64; ++u) { float4 a = w[u], q = xh[u]; acc += a.x*q.x + a.y*q.y + a.z*q.z + a.w*q.w; }
    #pragma unroll 8
    for (int u = 0; u < 64; ++u) { float4 a = w[64 + u], q = xc[u]; acc += a.x*q.x + a.y*q.y + a.z*q.z + a.w*q.w; }
    daf[b * 512 + d] = acc;
}

// ---------------- E3: e[s,b] -> exp(e)*mask ----------------
__global__ __launch_bounds__(256)
void dec_e_kernel(const ushort* __restrict__ encfeat, const float* __restrict__ daf,
                  const float* __restrict__ wv, const int* __restrict__ inputs,
                  float* __restrict__ exps)
{
    int s = blockIdx.x, t = threadIdx.x;
    int b = t >> 3, q = t & 7;
    const ushort* ef = encfeat + ((size_t)(s * B + b)) * 512 + q * 64;
    const float* dr = daf + b * 512 + q * 64;
    const float* wr = wv + q * 64;
    float p = 0.f;
    #pragma unroll 4
    for (int i = 0; i < 16; ++i) {
        uint2 u = *(const uint2*)(ef + i * 4);
        h2f x0 = asH2(u.x), x1 = asH2(u.y);
        int d = i * 4;
        p += tanhf_((float)x0.x + dr[d + 0]) * wr[d + 0];
        p += tanhf_((float)x0.y + dr[d + 1]) * wr[d + 1];
        p += tanhf_((float)x1.x + dr[d + 2]) * wr[d + 2];
        p += tanhf_((float)x1.y + dr[d + 3]) * wr[d + 3];
    }
    __shared__ float red[256];
    red[t] = p;
    __syncthreads();
    if (t < 32) {
        float e = 0.f;
        #pragma unroll
        for (int k = 0; k < 8; ++k) e += red[t * 8 + k];
        float m = (inputs[s * B + t] != 0) ? 1.f : 0.f;
        exps[s * B + t] = m * __expf(e);
    }
}

// ---------------- E4: softmax-normalize, context, p_gen, atts ----------------
__global__ __launch_bounds__(256)
void dec_ctx_kernel(const float* __restrict__ exps, const ushort* __restrict__ encout,
                    const float* __restrict__ h, const float* __restrict__ c,
                    float* __restrict__ ctx, const float* __restrict__ emb,
                    const int* __restrict__ toks, const float* __restrict__ upg,
                    const float* __restrict__ cpgp, const float* __restrict__ wpg,
                    float* __restrict__ pgen, float* __restrict__ attsout)
{
    int b = blockIdx.x, t = threadIdx.x;
    __shared__ float sc[400];
    __shared__ float red[256];
    float part = 0.f;
    for (int s = t; s < 400; s += 256) { float v = exps[s * 32 + b]; sc[s] = v; part += v; }
    red[t] = part;
    __syncthreads();
    for (int o = 128; o > 0; o >>= 1) { if (t < o) red[t] += red[t + o]; __syncthreads(); }
    float rinv = 1.f / red[0];
    // context (dims 2t, 2t+1)
    float a0 = 0.f, a1 = 0.f;
    #pragma unroll 4
    for (int s = 0; s < 400; ++s) {
        float w = sc[s];
        unsigned u = *(const unsigned*)(encout + ((size_t)(s * 32 + b)) * 512 + 2 * t);
        a0 += w * bf2f(u & 0xffffu);
        a1 += w * bf2f(u >> 16);
    }
    a0 *= rinv; a1 *= rinv;
    for (int s = t; s < 400; s += 256) attsout[s * 32 + b] = sc[s] * rinv;
    // p_gen partials
    float pp = a0 * wpg[2 * t] + a1 * wpg[2 * t + 1];
    int k0 = 2 * t;
    float dh0 = (k0 < 256) ? h[b * 256 + k0] : c[b * 256 + k0 - 256];
    float dh1 = (k0 + 1 < 256) ? h[b * 256 + k0 + 1] : c[b * 256 + k0 + 1 - 256];
    pp += dh0 * wpg[512 + k0] + dh1 * wpg[512 + k0 + 1];
    float co0 = ctx[b * 512 + t], co1 = ctx[b * 512 + t + 256];
    pp += co0 * upg[t] + co1 * upg[t + 256];
    if (t < 128) pp += emb[(size_t)toks[b] * 128 + t] * upg[512 + t];
    __syncthreads();
    red[t] = pp;
    __syncthreads();
    for (int o = 128; o > 0; o >>= 1) { if (t < o) red[t] += red[t + o]; __syncthreads(); }
    if (t == 0) pgen[b] = sigmoidf_(red[0] + cpgp[0]);
    __syncthreads();
    ctx[b * 512 + 2 * t] = a0;
    ctx[b * 512 + 2 * t + 1] = a1;
}

// ---------------- E4b: hid = [dh, context] @ W_o1^T + b_o1 -> bf16 ----------------
__global__ __launch_bounds__(256)
void dec_hid_kernel(const float* __restrict__ h, const float* __restrict__ c,
                    const float* __restrict__ ctx, const ushort* __restrict__ wo1bf,
                    const float* __restrict__ b_o1, ushort* __restrict__ hidbf)
{
    int g = blockIdx.x, b = g >> 2, dg = (g & 3) * 64;
    int t = threadIdx.x, d = dg + (t >> 2), kq = t & 3;
    const ushort* w = wo1bf + (size_t)d * 1024 + kq * 256;
    const float* xr = (kq == 0) ? h + b * 256 : (kq == 1) ? c + b * 256 : ctx + b * 512 + (kq - 2) * 256;
    float acc = 0.f;
    #pragma unroll 8
    for (int k = 0; k < 256; k += 4) {
        float4 x = *(const float4*)(xr + k);
        uint2 wu = *(const uint2*)(w + k);
        acc += x.x * bf2f(wu.x & 0xffffu) + x.y * bf2f(wu.x >> 16)
             + x.z * bf2f(wu.y & 0xffffu) + x.w * bf2f(wu.y >> 16);
    }
    __shared__ float red[256];
    red[t] = acc;
    __syncthreads();
    if (kq == 0) {
        float v = red[t] + red[t + 1] + red[t + 2] + red[t + 3] + b_o1[d];
        hidbf[b * 256 + d] = f2bf(v);
    }
}

// ---------------- E5b: sumV[b] = sum_v pbuf[b][v] ----------------
__global__ __launch_bounds__(256)
void dec_sumv_kernel(const float* __restrict__ pbuf, float* __restrict__ sumv)
{
    int b = blockIdx.x, t = threadIdx.x;
    const float* row = pbuf + (size_t)b * V;
    float acc = 0.f;
    for (int v = t; v < V; v += 256) acc += row[v];
    __shared__ float red[256];
    red[t] = acc;
    __syncthreads();
    for (int o = 128; o > 0; o >>= 1) { if (t < o) red[t] += red[t + o]; __syncthreads(); }
    if (t == 0) sumv[b] = red[0];
}

// ---------------- E6: write outs[t] ----------------
__global__ __launch_bounds__(256)
void dec_out_kernel(const float* __restrict__ pbuf, const float* __restrict__ pgen,
                    const float* __restrict__ sumv, float* __restrict__ outs)
{
    long id = (long)blockIdx.x * 256 + threadIdx.x;
    if (id >= (long)B * VO) return;
    int b = (int)(id / VO), v = (int)(id % VO);
    float val = 0.f;
    if (v < V) val = pgen[b] * pbuf[(size_t)b * V + v] / sumv[b];
    outs[id] = val;
}

// ---------------- final scatter (t = T-1) ----------------
__global__ __launch_bounds__(256)
void dec_scatter_kernel(const float* __restrict__ pgen, const int* __restrict__ tex,
                        const float* __restrict__ atts, float* __restrict__ outs)
{
    int id = blockIdx.x * 256 + threadIdx.x;   // s*32 + b
    int b = id & 31;
    float v = (1.f - pgen[b]) * atts[id];
    atomicAdd(outs + (size_t)b * VO + tex[id], v);
}

// ---------------- host ----------------
extern "C" void kernel_launch(void* const* d_in, const int* in_sizes, int n_in,
                              void* d_out, int out_size, void* d_ws, size_t ws_size,
                              hipStream_t stream)
{
    const int*   inputs  = (const int*)d_in[0];
    const int*   toksAll = (const int*)d_in[2];
    const int*   tex     = (const int*)d_in[3];
    const float* emb     = (const float*)d_in[5];
    const float* Wih_f   = (const float*)d_in[6];
    const float* Whh_f   = (const float*)d_in[7];
    const float* bih_f   = (const float*)d_in[8];
    const float* bhh_f   = (const float*)d_in[9];
    const float* Wih_b   = (const float*)d_in[10];
    const float* Whh_b   = (const float*)d_in[11];
    const float* bih_b   = (const float*)d_in[12];
    const float* bhh_b   = (const float*)d_in[13];
    const float* W_feat  = (const float*)d_in[14];
    const float* W_rh    = (const float*)d_in[15];
    const float* b_rh    = (const float*)d_in[16];
    const float* W_rc    = (const float*)d_in[17];
    const float* b_rc    = (const float*)d_in[18];
    const float* W_af    = (const float*)d_in[19];
    const float* b_af    = (const float*)d_in[20];
    const float* w_v     = (const float*)d_in[21];
    const float* W_ctx   = (const float*)d_in[22];
    const float* b_ctx   = (const float*)d_in[23];
    const float* dWih    = (const float*)d_in[24];
    const float* dWhh    = (const float*)d_in[25];
    const float* dbih    = (const float*)d_in[26];
    const float* dbhh    = (const float*)d_in[27];
    const float* W_pg    = (const float*)d_in[28];
    const float* b_pg    = (const float*)d_in[29];
    const float* W_o1    = (const float*)d_in[30];
    const float* b_o1    = (const float*)d_in[31];
    const float* W_o2    = (const float*)d_in[32];
    const float* b_o2    = (const float*)d_in[33];

    char* wsb = (char*)d_ws;
    ushort*   emb2d   = (ushort*)(wsb + OFF_EMB2D);
    ushort*   wihcat  = (ushort*)(wsb + OFF_WIHCAT);
    float*    biasx   = (float*)(wsb + OFF_BIASX);
    ushort*   wfeatbf = (ushort*)(wsb + OFF_WFEAT);
    ushort*   wo2bf   = (ushort*)(wsb + OFF_WO2);
    ushort*   wo1bf   = (ushort*)(wsb + OFF_WO1);
    unsigned* whhpk   = (unsigned*)(wsb + OFF_WHHPK);
    float*    wcm     = (float*)(wsb + OFF_WC);
    float*    bcv     = (float*)(wsb + OFF_BC);
    float*    upg     = (float*)(wsb + OFF_UPG);
    float*    cpgp    = (float*)(wsb + OFF_CPG);
    ushort*   xproj   = (ushort*)(wsb + OFF_XPROJ);
    ushort*   encout  = (ushort*)(wsb + OFF_ENCOUT);
    ushort*   encfeat = (ushort*)(wsb + OFF_ENCFEAT);
    float*    hfin    = (float*)(wsb + OFF_HFIN);
    float*    cfin    = (float*)(wsb + OFF_CFIN);
    float*    hdec    = (float*)(wsb + OFF_HDEC);
    float*    cdec    = (float*)(wsb + OFF_CDEC);
    float*    ctx     = (float*)(wsb + OFF_CTX);
    float*    daf     = (float*)(wsb + OFF_DAF);
    float*    exps    = (float*)(wsb + OFF_EXPS);
    float*    pgen    = (float*)(wsb + OFF_PGEN);
    ushort*   hidbf   = (ushort*)(wsb + OFF_HIDBF);
    float*    sumv    = (float*)(wsb + OFF_SUMV);
    float*    pbuf    = (float*)(wsb + OFF_PBUF);

    float* outs = (float*)d_out;
    float* atts = outs + (size_t)T * B * VO;

    int prep_blocks = (int)((PREP_TOTAL + 255) / 256);
    prep_kernel<<<prep_blocks, 256, 0, stream>>>(
        Wih_f, Wih_b, bih_f, bhh_f, bih_b, bhh_b, W_feat, W_o2, W_o1, Whh_f, Whh_b,
        dWih, W_ctx, W_pg, b_pg, b_ctx, dbih, dbhh, emb, inputs,
        emb2d, wihcat, biasx, wfeatbf, wo2bf, wo1bf, whhpk, wcm, upg, cpgp, bcv);

    // Xproj = emb2d @ [Wih_f; Wih_b]^T + (bih+bhh), f16 output
    gemm_nt<64, 64, 1, true, false><<<dim3(2048 / 64, SB / 64), 256, 0, stream>>>(
        emb2d, 128, wihcat, 128, (void*)xproj, 2048, biasx, SB, 2048, 128);

    enc_kernel<<<64, 256, 0, stream>>>(xproj, (const uint4*)whhpk, encout, hfin, cfin);

    initdec_kernel<<<32, 256, 0, stream>>>(hfin, cfin, W_rh, b_rh, W_rc, b_rc, hdec, cdec, ctx);

    // enc_feat = enc_out @ W_feat^T, f16 output
    gemm_nt<64, 64, 1, false, false><<<dim3(512 / 64, SB / 64), 256, 0, stream>>>(
        encout, 512, wfeatbf, 512, (void*)encfeat, 512, nullptr, SB, 512, 512);

    for (int t = 0; t < T; ++t) {
        int in = t & 1, op = in ^ 1;
        float* hin  = hdec + (size_t)in * B * H;
        float* cin  = cdec + (size_t)in * B * H;
        float* hout = hdec + (size_t)op * B * H;
        float* cout = cdec + (size_t)op * B * H;
        const float* attsPrev = (t == 0) ? atts : atts + (size_t)(t - 1) * SB;
        float* outsPrev = (t == 0) ? outs : outs + (size_t)(t - 1) * B * VO;

        dec_lstm_kernel<<<178, 256, 0, stream>>>(ctx, emb, toksAll + t * B, wcm, dWhh, bcv,
                                                 hin, cin, hout, cout,
                                                 t - 1, pgen, tex, attsPrev, outsPrev);
        dec_daf_kernel<<<64, 256, 0, stream>>>(hout, cout, W_af, b_af, daf);
        dec_e_kernel<<<400, 256, 0, stream>>>(encfeat, daf, w_v, inputs, exps);
        dec_ctx_kernel<<<32, 256, 0, stream>>>(exps, encout, hout, cout, ctx, emb,
                                               toksAll + t * B, upg, cpgp, W_pg, pgen,
                                               atts + (size_t)t * SB);
        dec_hid_kernel<<<128, 256, 0, stream>>>(hout, cout, ctx, wo1bf, b_o1, hidbf);
        gemm_nt<32, 128, 2, true, true><<<dim3(391, 1), 256, 0, stream>>>(
            hidbf, 256, wo2bf, 256, (void*)pbuf, V, b_o2, 32, V, 256);
        dec_sumv_kernel<<<32, 256, 0, stream>>>(pbuf, sumv);
        dec_out_kernel<<<(int)(((long)B * VO + 255) / 256), 256, 0, stream>>>(
            pbuf, pgen, sumv, outs + (size_t)t * B * VO);
    }
    dec_scatter_kernel<<<50, 256, 0, stream>>>(pgen, tex, atts + (size_t)(T - 1) * SB,
                                               outs + (size_t)(T - 1) * B * VO);
}

// Round 2
// 7845.277 us; speedup vs baseline: 1.1119x; 1.1119x over previous
//
#include <hip/hip_runtime.h>

#define DEV static __device__ __forceinline__

typedef short  s16x8 __attribute__((ext_vector_type(8)));
typedef float  f32x4 __attribute__((ext_vector_type(4)));
typedef _Float16 h2f __attribute__((ext_vector_type(2)));

constexpr int S = 400, B = 32, T = 32, V = 50000, OOV = 50, E = 128, H = 256;
constexpr int VO = V + OOV, SB = S * B;

DEV ushort f2bf(float x) {
    union { float f; unsigned u; } a; a.f = x;
    unsigned r = (a.u + 0x7fffu + ((a.u >> 16) & 1u)) >> 16;
    return (ushort)r;
}
DEV float bf2f(unsigned b) {
    union { unsigned u; float f; } a; a.u = b << 16; return a.f;
}
DEV float sigmoidf_(float x) { return 1.0f / (1.0f + __expf(-x)); }
DEV float tanhf_(float x) { float e = __expf(2.0f * x); return 1.0f - 2.0f / (e + 1.0f); }
DEV h2f asH2(unsigned u) { union { unsigned u; h2f h; } x; x.u = u; return x.h; }

#if __has_builtin(__builtin_amdgcn_fdot2)
DEV float dot2(h2f a, h2f b, float c) { return __builtin_amdgcn_fdot2(a, b, c, false); }
#else
DEV float dot2(h2f a, h2f b, float c) { return c + (float)a.x * (float)b.x + (float)a.y * (float)b.y; }
#endif

// ---------------- workspace layout ----------------
constexpr size_t SZ_EMB2D  = (size_t)SB * E * 2;        // bf16
constexpr size_t SZ_WIHCAT = (size_t)2048 * 128 * 2;    // bf16
constexpr size_t SZ_BIASX  = 2048 * 4;
constexpr size_t SZ_WFEAT  = (size_t)512 * 512 * 2;     // bf16
constexpr size_t SZ_WO2    = (size_t)V * H * 2;         // bf16
constexpr size_t SZ_WO1T   = (size_t)1024 * 256 * 2;    // bf16 transposed [k][d]
constexpr size_t SZ_WHH2   = (size_t)2 * 64 * 512 * 16; // f16 packed persistent layout
constexpr size_t SZ_WAFT   = (size_t)512 * 512 * 4;     // f32 transposed [k][d]
constexpr size_t SZ_WRHT   = (size_t)512 * 256 * 4;     // f32 transposed
constexpr size_t SZ_WRCT   = (size_t)512 * 256 * 4;
constexpr size_t SZ_WC     = (size_t)1024 * 640 * 4;
constexpr size_t SZ_BC     = 1024 * 4;
constexpr size_t SZ_UPG    = 640 * 4;
constexpr size_t SZ_CPG    = 256;
constexpr size_t SZ_XPROJ  = (size_t)SB * 2048 * 2;     // f16 (aliased by pbuf later)
constexpr size_t SZ_ENCOUT = (size_t)SB * 512 * 2;      // bf16
constexpr size_t SZ_ENCFEAT= (size_t)SB * 512 * 2;      // f16
constexpr size_t SZ_HFIN   = (size_t)2 * B * H * 4;
constexpr size_t SZ_HDEC   = (size_t)2 * B * H * 4;
constexpr size_t SZ_CTX    = (size_t)B * 512 * 4;
constexpr size_t SZ_PGEN   = 256;
constexpr size_t SZ_HIDBF  = (size_t)B * 256 * 2;

constexpr size_t OFF_EMB2D  = 0;
constexpr size_t OFF_WIHCAT = OFF_EMB2D  + SZ_EMB2D;
constexpr size_t OFF_BIASX  = OFF_WIHCAT + SZ_WIHCAT;
constexpr size_t OFF_WFEAT  = OFF_BIASX  + SZ_BIASX;
constexpr size_t OFF_WO2    = OFF_WFEAT  + SZ_WFEAT;
constexpr size_t OFF_WO1T   = OFF_WO2    + SZ_WO2;
constexpr size_t OFF_WHH2   = OFF_WO1T   + SZ_WO1T;
constexpr size_t OFF_WAFT   = OFF_WHH2   + SZ_WHH2;
constexpr size_t OFF_WRHT   = OFF_WAFT   + SZ_WAFT;
constexpr size_t OFF_WRCT   = OFF_WRHT   + SZ_WRHT;
constexpr size_t OFF_WC     = OFF_WRCT   + SZ_WRCT;
constexpr size_t OFF_BC     = OFF_WC     + SZ_WC;
constexpr size_t OFF_UPG    = OFF_BC     + SZ_BC;
constexpr size_t OFF_CPG    = OFF_UPG    + SZ_UPG;
constexpr size_t OFF_XPROJ  = OFF_CPG    + SZ_CPG;
constexpr size_t OFF_ENCOUT = OFF_XPROJ  + SZ_XPROJ;
constexpr size_t OFF_ENCFEAT= OFF_ENCOUT + SZ_ENCOUT;
constexpr size_t OFF_HFIN   = OFF_ENCFEAT+ SZ_ENCFEAT;
constexpr size_t OFF_CFIN   = OFF_HFIN   + SZ_HFIN;
constexpr size_t OFF_HDEC   = OFF_CFIN   + SZ_HFIN;
constexpr size_t OFF_CDEC   = OFF_HDEC   + SZ_HDEC;
constexpr size_t OFF_CTX    = OFF_CDEC   + SZ_HDEC;
constexpr size_t OFF_PGEN   = OFF_CTX    + SZ_CTX;
constexpr size_t OFF_HIDBF  = OFF_PGEN   + SZ_PGEN;
constexpr size_t OFF_PBUF   = OFF_XPROJ;  // alias: xproj dead after encoder

// ---------------- prep sizes ----------------
constexpr long N1  = 2048L*128;    // wihcat
constexpr long N2  = 2048;         // biasx
constexpr long N3  = 512L*512;     // wfeat
constexpr long N4  = (long)V*H;    // wo2
constexpr long N5  = 1024L*256;    // wo1T (transposed)
constexpr long N6  = 2L*64*512*4;  // whh2 dwords (persistent layout)
constexpr long N7  = 1024L*640;    // wcm
constexpr long N8  = 640;          // upg
constexpr long N9  = 1;            // cpg
constexpr long N10 = 1024;         // bcv
constexpr long N11 = (long)SB*E;   // emb2d
constexpr long N12 = 512L*512;     // wafT
constexpr long N13 = 512L*256;     // wrhT
constexpr long N14 = 512L*256;     // wrcT
constexpr long PREP_TOTAL = N1+N2+N3+N4+N5+N6+N7+N8+N9+N10+N11+N12+N13+N14;

__global__ __launch_bounds__(256)
void prep_kernel(const float* __restrict__ Wih_f, const float* __restrict__ Wih_b,
                 const float* __restrict__ bih_f, const float* __restrict__ bhh_f,
                 const float* __restrict__ bih_b, const float* __restrict__ bhh_b,
                 const float* __restrict__ W_feat, const float* __restrict__ W_o2,
                 const float* __restrict__ W_o1, const float* __restrict__ Whh_f,
                 const float* __restrict__ Whh_b, const float* __restrict__ dWih,
                 const float* __restrict__ W_ctx, const float* __restrict__ W_pg,
                 const float* __restrict__ b_pg, const float* __restrict__ b_ctx,
                 const float* __restrict__ dbih, const float* __restrict__ dbhh,
                 const float* __restrict__ emb, const int* __restrict__ inputs,
                 const float* __restrict__ W_af, const float* __restrict__ W_rh,
                 const float* __restrict__ W_rc,
                 ushort* __restrict__ emb2d, ushort* __restrict__ wihcat,
                 float* __restrict__ biasx, ushort* __restrict__ wfeatbf,
                 ushort* __restrict__ wo2bf, ushort* __restrict__ wo1T,
                 unsigned* __restrict__ whh2, float* __restrict__ wcm,
                 float* __restrict__ upg, float* __restrict__ cpgp, float* __restrict__ bcv,
                 float* __restrict__ wafT, float* __restrict__ wrhT, float* __restrict__ wrcT)
{
    long id = (long)blockIdx.x * 256 + threadIdx.x;
    if (id < N1) { int r = id >> 7, e = id & 127;
        float v = (r < 1024) ? Wih_f[r*128+e] : Wih_b[(r-1024)*128+e];
        wihcat[id] = f2bf(v); return; }
    id -= N1;
    if (id < N2) { biasx[id] = (id < 1024) ? bih_f[id]+bhh_f[id] : bih_b[id-1024]+bhh_b[id-1024]; return; }
    id -= N2;
    if (id < N3) { wfeatbf[id] = f2bf(W_feat[id]); return; }
    id -= N3;
    if (id < N4) { wo2bf[id] = f2bf(W_o2[id]); return; }
    id -= N4;
    if (id < N5) { int d = id & 255; long k = id >> 8;   // wo1T[k][d]
        wo1T[id] = f2bf(W_o1[(size_t)d * 1024 + k]); return; }
    id -= N5;
    if (id < N6) {
        int q = id & 3; long e = id >> 2;
        int t = e & 511; e >>= 9; int c = e & 63; int dir = (int)(e >> 6);
        int j = t & 255, kh = t >> 8, g = c >> 4, pb = c & 15;
        int p = pb * 4 + q, k0 = kh * 128 + 2 * p, row = g * 256 + j;
        const float* W = dir ? Whh_b : Whh_f;
        h2f hv; hv.x = (_Float16)W[(size_t)row*256 + k0]; hv.y = (_Float16)W[(size_t)row*256 + k0 + 1];
        whh2[id] = __builtin_bit_cast(unsigned, hv); return; }
    id -= N6;
    if (id < N7) { int g = id / 640, u = id % 640;
        float acc = 0.f;
        for (int e = 0; e < 128; ++e) acc += dWih[g*128+e] * W_ctx[e*640+u];
        wcm[id] = acc; return; }
    id -= N7;
    if (id < N8) { float acc = 0.f;
        for (int e = 0; e < 128; ++e) acc += W_pg[1024+e] * W_ctx[e*640+(int)id];
        upg[id] = acc; return; }
    id -= N8;
    if (id < N9) { float acc = b_pg[0];
        for (int e = 0; e < 128; ++e) acc += W_pg[1024+e] * b_ctx[e];
        cpgp[0] = acc; return; }
    id -= N9;
    if (id < N10) { float acc = dbih[id] + dbhh[id];
        for (int e = 0; e < 128; ++e) acc += dWih[id*128+e] * b_ctx[e];
        bcv[id] = acc; return; }
    id -= N10;
    if (id < N11) { long sb = id >> 7; int e = id & 127;
        emb2d[id] = f2bf(emb[(size_t)inputs[sb]*128 + e]); return; }
    id -= N11;
    if (id < N12) { int d = id & 511; long k = id >> 9;  // wafT[k][d]
        wafT[id] = W_af[(size_t)d * 512 + k]; return; }
    id -= N12;
    if (id < N13) { int j = id & 255; long k = id >> 8;  // wrhT[k][j]
        wrhT[id] = W_rh[(size_t)j * 512 + k]; return; }
    id -= N13;
    if (id < N14) { int j = id & 255; long k = id >> 8;
        wrcT[id] = W_rc[(size_t)j * 512 + k]; return; }
}

// ---------------- generic bf16 MFMA GEMM: C = A(MxK) * B(NxK)^T (+bias) ----------------
// MODE: 0 = f32 store, 1 = f16 store, 2 = f32 exp(store)
template<int BM, int BN, int MODE, bool BIAS, bool SWZ>
__global__ __launch_bounds__(256)
void gemm_nt(const ushort* __restrict__ A, int lda, const ushort* __restrict__ Bm, int ldb,
             void* __restrict__ Cp, int ldc, const float* __restrict__ bias,
             int M, int N, int K)
{
    constexpr int WN = BN / 32;
    __shared__ ushort sA[BM * 32];
    __shared__ ushort sB[BN * 32];
    int tid = threadIdx.x, lane = tid & 63, wid = tid >> 6;
    int wm = wid / WN, wn = wid % WN;
    int mb = blockIdx.y, nb = blockIdx.x;
    if (SWZ) {
        int n = gridDim.x, x = nb & 7, y = nb >> 3, q = n >> 3, r = n & 7;
        nb = (x < r ? x * (q + 1) : r * (q + 1) + (x - r) * q) + y;
    }
    int l15 = lane & 15, lg = lane >> 4;
    f32x4 acc[2][2] = {};
    for (int k0 = 0; k0 < K; k0 += 32) {
        for (int idx = tid; idx < BM * 4; idx += 256) {
            int r = idx >> 2, kc = (idx & 3) << 3;
            int row = mb * BM + r;
            uint4 v = make_uint4(0u, 0u, 0u, 0u);
            if (row < M) v = *(const uint4*)(A + (size_t)row * lda + k0 + kc);
            *(uint4*)(&sA[r * 32 + kc]) = v;
        }
        for (int idx = tid; idx < BN * 4; idx += 256) {
            int r = idx >> 2, kc = (idx & 3) << 3;
            int row = nb * BN + r;
            uint4 v = make_uint4(0u, 0u, 0u, 0u);
            if (row < N) v = *(const uint4*)(Bm + (size_t)row * ldb + k0 + kc);
            *(uint4*)(&sB[r * 32 + kc]) = v;
        }
        __syncthreads();
        s16x8 a0 = *(const s16x8*)(&sA[(wm * 32 + l15) * 32 + lg * 8]);
        s16x8 a1 = *(const s16x8*)(&sA[(wm * 32 + 16 + l15) * 32 + lg * 8]);
        s16x8 b0 = *(const s16x8*)(&sB[(wn * 32 + l15) * 32 + lg * 8]);
        s16x8 b1 = *(const s16x8*)(&sB[(wn * 32 + 16 + l15) * 32 + lg * 8]);
        acc[0][0] = __builtin_amdgcn_mfma_f32_16x16x32_bf16(a0, b0, acc[0][0], 0, 0, 0);
        acc[0][1] = __builtin_amdgcn_mfma_f32_16x16x32_bf16(a0, b1, acc[0][1], 0, 0, 0);
        acc[1][0] = __builtin_amdgcn_mfma_f32_16x16x32_bf16(a1, b0, acc[1][0], 0, 0, 0);
        acc[1][1] = __builtin_amdgcn_mfma_f32_16x16x32_bf16(a1, b1, acc[1][1], 0, 0, 0);
        __syncthreads();
    }
    int cb = nb * BN + wn * 32, rb = mb * BM + wm * 32;
    #pragma unroll
    for (int mf = 0; mf < 2; ++mf)
    #pragma unroll
    for (int nf = 0; nf < 2; ++nf) {
        int col = cb + nf * 16 + l15;
        float bv = 0.f;
        if (BIAS) { if (col < N) bv = bias[col]; }
        #pragma unroll
        for (int r = 0; r < 4; ++r) {
            int row = rb + mf * 16 + lg * 4 + r;
            if (row < M && col < N) {
                float v = acc[mf][nf][r] + bv;
                if (MODE == 0)      ((float*)Cp)[(size_t)row * ldc + col] = v;
                else if (MODE == 1) ((ushort*)Cp)[(size_t)row * ldc + col] = __builtin_bit_cast(ushort, (_Float16)v);
                else                ((float*)Cp)[(size_t)row * ldc + col] = __expf(v);
            }
        }
    }
}

// ---------------- encoder: persistent weights in VGPRs + LDS ----------------
// 64 WGs (one per dir,b), 512 threads: thread (j = t&255, kh = t>>8) computes
// partial gates for k-half kh. Weights: 46 uint4 chunks in regs + 18 in LDS.
__global__ __launch_bounds__(512, 2)
void enc_kernel(const ushort* __restrict__ xproj, const uint4* __restrict__ whh2,
                ushort* __restrict__ encout, float* __restrict__ hfin, float* __restrict__ cfin)
{
    __shared__ uint4  wlds[18 * 512];        // 144 KB: gg chunks pb14,15 + all o-gate
    __shared__ float  pred[2 * 4 * 256];     // [kh][g][j] 8 KB
    __shared__ __attribute__((aligned(16))) ushort hh16[256];
    int b = blockIdx.x & 31, dir = blockIdx.x >> 5;
    int t = threadIdx.x, j = t & 255, kh = t >> 8;
    const uint4* gw = whh2 + ((size_t)dir * 64) * 512 + t;
    uint4 wreg[46];
    #pragma unroll
    for (int c = 0; c < 46; ++c) wreg[c] = gw[(size_t)c * 512];
    #pragma unroll
    for (int c = 46; c < 64; ++c) wlds[(c - 46) * 512 + t] = gw[(size_t)c * 512];
    if (t < 256) hh16[t] = 0;
    float cst = 0.f, hst = 0.f;
    __syncthreads();
    #pragma unroll 1
    for (int step = 0; step < S; ++step) {
        int s = dir ? (S - 1 - step) : step;
        ushort rx0 = 0, rx1 = 0, rx2 = 0, rx3 = 0;
        if (t < 256) {   // wave-uniform branch; loads stay in flight through dot phase
            const ushort* xp = xproj + ((size_t)(s * B + b)) * 2048 + dir * 1024 + j;
            rx0 = xp[0]; rx1 = xp[256]; rx2 = xp[512]; rx3 = xp[768];
        }
        float a0 = 0.f, a1 = 0.f, a2 = 0.f, a3 = 0.f;
        #pragma unroll
        for (int pb = 0; pb < 16; ++pb) {
            uint4 hp = *(const uint4*)(hh16 + kh * 128 + pb * 8);
            uint4 wi = wreg[pb];
            uint4 wf = wreg[16 + pb];
            uint4 wg = (pb < 14) ? wreg[32 + pb] : wlds[(pb - 14) * 512 + t];
            uint4 wo = wlds[(pb + 2) * 512 + t];
            h2f p0 = asH2(hp.x), p1 = asH2(hp.y), p2 = asH2(hp.z), p3 = asH2(hp.w);
            a0 = dot2(p0, asH2(wi.x), a0); a0 = dot2(p1, asH2(wi.y), a0);
            a0 = dot2(p2, asH2(wi.z), a0); a0 = dot2(p3, asH2(wi.w), a0);
            a1 = dot2(p0, asH2(wf.x), a1); a1 = dot2(p1, asH2(wf.y), a1);
            a1 = dot2(p2, asH2(wf.z), a1); a1 = dot2(p3, asH2(wf.w), a1);
            a2 = dot2(p0, asH2(wg.x), a2); a2 = dot2(p1, asH2(wg.y), a2);
            a2 = dot2(p2, asH2(wg.z), a2); a2 = dot2(p3, asH2(wg.w), a2);
            a3 = dot2(p0, asH2(wo.x), a3); a3 = dot2(p1, asH2(wo.y), a3);
            a3 = dot2(p2, asH2(wo.z), a3); a3 = dot2(p3, asH2(wo.w), a3);
        }
        pred[kh * 1024 + 0 * 256 + j] = a0;
        pred[kh * 1024 + 1 * 256 + j] = a1;
        pred[kh * 1024 + 2 * 256 + j] = a2;
        pred[kh * 1024 + 3 * 256 + j] = a3;
        __syncthreads();
        if (t < 256) {
            float gi = pred[j]       + pred[1024 + j]       + (float)__builtin_bit_cast(_Float16, rx0);
            float gf = pred[256 + j] + pred[1024 + 256 + j] + (float)__builtin_bit_cast(_Float16, rx1);
            float gg = pred[512 + j] + pred[1024 + 512 + j] + (float)__builtin_bit_cast(_Float16, rx2);
            float go = pred[768 + j] + pred[1024 + 768 + j] + (float)__builtin_bit_cast(_Float16, rx3);
            cst = sigmoidf_(gf) * cst + sigmoidf_(gi) * tanhf_(gg);
            hst = sigmoidf_(go) * tanhf_(cst);
            encout[((size_t)(s * B + b)) * 512 + dir * 256 + j] = f2bf(hst);
            hh16[j] = __builtin_bit_cast(ushort, (_Float16)hst);
        }
        __syncthreads();
    }
    if (t < 256) {
        hfin[(dir * 32 + b) * 256 + j] = hst;
        cfin[(dir * 32 + b) * 256 + j] = cst;
    }
}

// ---------------- decoder init ----------------
__global__ __launch_bounds__(256)
void initdec_kernel(const float* __restrict__ hfin, const float* __restrict__ cfin,
                    const float* __restrict__ wrhT, const float* __restrict__ b_rh,
                    const float* __restrict__ wrcT, const float* __restrict__ b_rc,
                    float* __restrict__ hdec0, float* __restrict__ cdec0, float* __restrict__ ctx)
{
    int b = blockIdx.x, j = threadIdx.x;
    float ah = b_rh[j], ac = b_rc[j];
    for (int k = 0; k < 512; ++k) {
        float hv = (k < 256) ? hfin[b * 256 + k] : hfin[(32 + b) * 256 + k - 256];
        float cv = (k < 256) ? cfin[b * 256 + k] : cfin[(32 + b) * 256 + k - 256];
        ah += hv * wrhT[k * 256 + j];
        ac += cv * wrcT[k * 256 + j];
    }
    hdec0[b * 256 + j] = fmaxf(ah, 0.f);
    cdec0[b * 256 + j] = fmaxf(ac, 0.f);
    ctx[b * 512 + j] = 0.f;
    ctx[b * 512 + 256 + j] = 0.f;
}

// ---------------- D1: decoder LSTM ----------------
__global__ __launch_bounds__(256)
void dec_lstm_kernel(const float* __restrict__ ctx, const float* __restrict__ emb,
                     const int* __restrict__ toks, const float* __restrict__ wcm,
                     const float* __restrict__ whh, const float* __restrict__ bcv,
                     const float* __restrict__ hprev, const float* __restrict__ cprev,
                     float* __restrict__ hnew, float* __restrict__ cnew)
{
    int t = threadIdx.x;
    int b = t & 31, ci = t >> 5;
    int gi = ci >> 1, jj = ci & 1;
    int j = (blockIdx.x << 1) + jj;
    int col = gi * 256 + j;
    float acc = bcv[col];
    {
        const float4* w = (const float4*)(wcm + (size_t)col * 640);
        const float4* x = (const float4*)(ctx + b * 512);
        #pragma unroll 8
        for (int u = 0; u < 128; ++u) { float4 a = w[u], q = x[u]; acc += a.x*q.x + a.y*q.y + a.z*q.z + a.w*q.w; }
        const float4* w2 = (const float4*)(wcm + (size_t)col * 640 + 512);
        const float4* x2 = (const float4*)(emb + (size_t)toks[b] * 128);
        #pragma unroll 8
        for (int u = 0; u < 32; ++u) { float4 a = w2[u], q = x2[u]; acc += a.x*q.x + a.y*q.y + a.z*q.z + a.w*q.w; }
        const float4* w3 = (const float4*)(whh + (size_t)col * 256);
        const float4* x3 = (const float4*)(hprev + b * 256);
        #pragma unroll 8
        for (int u = 0; u < 64; ++u) { float4 a = w3[u], q = x3[u]; acc += a.x*q.x + a.y*q.y + a.z*q.z + a.w*q.w; }
    }
    __shared__ float pre[256];
    pre[t] = acc;     // pre[ci*32 + b]
    __syncthreads();
    if (t < 64) {
        int b2 = t & 31, q = t >> 5;
        int j2 = (blockIdx.x << 1) + q;
        float iv = pre[(0 + q) * 32 + b2];
        float fv = pre[(2 + q) * 32 + b2];
        float gv = pre[(4 + q) * 32 + b2];
        float ov = pre[(6 + q) * 32 + b2];
        float cp = cprev[b2 * 256 + j2];
        float cn = sigmoidf_(fv) * cp + sigmoidf_(iv) * tanhf_(gv);
        float hn = sigmoidf_(ov) * tanhf_(cn);
        cnew[b2 * 256 + j2] = cn;
        hnew[b2 * 256 + j2] = hn;
    }
}

// ---------------- D2: fused attention (daf, e, softmax, ctx, pgen, hid) ----------------
// one block per batch row b, 512 threads
__global__ __launch_bounds__(512)
void dec_attn_kernel(const float* __restrict__ h, const float* __restrict__ c,
                     const float* __restrict__ wafT, const float* __restrict__ b_af,
                     const ushort* __restrict__ encfeat, const float* __restrict__ wv,
                     const int* __restrict__ inputs, const ushort* __restrict__ encout,
                     float* __restrict__ ctx, const float* __restrict__ emb,
                     const int* __restrict__ toks, const float* __restrict__ upg,
                     const float* __restrict__ cpgp, const float* __restrict__ wpg,
                     const ushort* __restrict__ wo1T, const float* __restrict__ b_o1,
                     float* __restrict__ pgen, float* __restrict__ attsout,
                     ushort* __restrict__ hidbf)
{
    int b = blockIdx.x, t = threadIdx.x;
    __shared__ float hc[512];
    __shared__ float dafL[8 * 65];   // padded: [q][d_local], stride 65 breaks bank aliasing
    __shared__ float sc[400];
    __shared__ float red[512];
    __shared__ float ctxL[512];
    // P0: stage [h, c]
    hc[t] = (t < 256) ? h[b * 256 + t] : c[b * 256 + t - 256];
    __syncthreads();
    // P1: daf[d] = b_af[d] + sum_k hc[k] * W_af[d][k]   (coalesced via wafT[k][d])
    {
        float acc = b_af[t];
        #pragma unroll 4
        for (int k = 0; k < 512; ++k) acc += hc[k] * wafT[k * 512 + t];
        dafL[(t >> 6) * 65 + (t & 63)] = acc;
    }
    __syncthreads();
    // P2: e[s] -> exp, masked
    for (int base = 0; base < 400; base += 64) {
        int sloc = base + (t >> 3);
        float p = 0.f;
        if (sloc < 400) {
            int q = t & 7;
            const ushort* ef = encfeat + ((size_t)(sloc * B + b)) * 512 + q * 64;
            const float* dr = dafL + q * 65;
            const float* wr = wv + q * 64;
            #pragma unroll 4
            for (int i = 0; i < 16; ++i) {
                uint2 u = *(const uint2*)(ef + i * 4);
                h2f e0 = asH2(u.x), e1 = asH2(u.y);
                int d = i * 4;
                p += tanhf_((float)e0.x + dr[d + 0]) * wr[d + 0];
                p += tanhf_((float)e0.y + dr[d + 1]) * wr[d + 1];
                p += tanhf_((float)e1.x + dr[d + 2]) * wr[d + 2];
                p += tanhf_((float)e1.y + dr[d + 3]) * wr[d + 3];
            }
        }
        p += __shfl_xor(p, 1);
        p += __shfl_xor(p, 2);
        p += __shfl_xor(p, 4);
        if (sloc < 400 && (t & 7) == 0) {
            float m = (inputs[sloc * B + b] != 0) ? 1.f : 0.f;
            sc[sloc] = m * __expf(p);
        }
    }
    __syncthreads();
    // P3: normalize + write atts
    red[t] = (t < 400) ? sc[t] : 0.f;
    __syncthreads();
    for (int o = 256; o > 0; o >>= 1) { if (t < o) red[t] += red[t + o]; __syncthreads(); }
    float rinv = 1.f / red[0];
    if (t < 400) { float an = sc[t] * rinv; sc[t] = an; attsout[t * 32 + b] = an; }
    __syncthreads();
    // P4: context dim t
    float anew = 0.f;
    {
        const ushort* ebase = encout + (size_t)b * 512 + t;
        #pragma unroll 4
        for (int s = 0; s < 400; ++s) anew += sc[s] * bf2f(ebase[(size_t)s * B * 512]);
    }
    // P5: p_gen partials (reads PREV ctx from global before overwrite)
    {
        float pp = anew * wpg[t] + hc[t] * wpg[512 + t] + ctx[b * 512 + t] * upg[t];
        if (t < 128) pp += emb[(size_t)toks[b] * 128 + t] * upg[512 + t];
        __syncthreads();
        red[t] = pp;
        __syncthreads();
        for (int o = 256; o > 0; o >>= 1) { if (t < o) red[t] += red[t + o]; __syncthreads(); }
        if (t == 0) pgen[b] = sigmoidf_(red[0] + cpgp[0]);
    }
    // P6: commit new ctx
    ctx[b * 512 + t] = anew;
    ctxL[t] = anew;
    __syncthreads();
    // P7: hid[d] = [hc(512), ctx(512)] @ W_o1[d]^T + b_o1[d]; 2 threads per d
    {
        int d = t >> 1, khp = t & 1;
        float acc = 0.f;
        const ushort* wbase = wo1T + (size_t)khp * 512 * 256 + d;
        const float* xs = khp ? ctxL : hc;
        #pragma unroll 8
        for (int k = 0; k < 512; ++k) acc += xs[k] * bf2f(wbase[(size_t)k * 256]);
        acc += __shfl_xor(acc, 1);
        if (khp == 0) hidbf[b * 256 + d] = f2bf(acc + b_o1[d]);
    }
}

// ---------------- D4: row-sum, scale+write outs, scatter ----------------
__global__ __launch_bounds__(256)
void dec_out_kernel(const float* __restrict__ pbuf, const float* __restrict__ pgen,
                    const int* __restrict__ tex, const float* __restrict__ atts_t,
                    float* __restrict__ outs_t)
{
    int b = blockIdx.x, t = threadIdx.x;
    const float4* row4 = (const float4*)(pbuf + (size_t)b * V);
    float part = 0.f;
    for (int i = t; i < V / 4; i += 256) { float4 v = row4[i]; part += v.x + v.y + v.z + v.w; }
    __shared__ float red[256];
    red[t] = part;
    __syncthreads();
    for (int o = 128; o > 0; o >>= 1) { if (t < o) red[t] += red[t + o]; __syncthreads(); }
    float pg = pgen[b];
    float sca = pg / red[0];
    float* orow = outs_t + (size_t)b * VO;
    float2* orow2 = (float2*)orow;
    const float2* prow2 = (const float2*)(pbuf + (size_t)b * V);
    for (int i = t; i < V / 2; i += 256) { float2 v = prow2[i]; orow2[i] = make_float2(v.x * sca, v.y * sca); }
    if (t < OOV) orow[V + t] = 0.f;
    __syncthreads();
    float om = 1.f - pg;
    for (int si = t; si < 400; si += 256)
        atomicAdd(orow + tex[si * 32 + b], om * atts_t[si * 32 + b]);
}

// ---------------- host ----------------
extern "C" void kernel_launch(void* const* d_in, const int* in_sizes, int n_in,
                              void* d_out, int out_size, void* d_ws, size_t ws_size,
                              hipStream_t stream)
{
    const int*   inputs  = (const int*)d_in[0];
    const int*   toksAll = (const int*)d_in[2];
    const int*   tex     = (const int*)d_in[3];
    const float* emb     = (const float*)d_in[5];
    const float* Wih_f   = (const float*)d_in[6];
    const float* Whh_f   = (const float*)d_in[7];
    const float* bih_f   = (const float*)d_in[8];
    const float* bhh_f   = (const float*)d_in[9];
    const float* Wih_b   = (const float*)d_in[10];
    const float* Whh_b   = (const float*)d_in[11];
    const float* bih_b   = (const float*)d_in[12];
    const float* bhh_b   = (const float*)d_in[13];
    const float* W_feat  = (const float*)d_in[14];
    const float* W_rh    = (const float*)d_in[15];
    const float* b_rh    = (const float*)d_in[16];
    const float* W_rc    = (const float*)d_in[17];
    const float* b_rc    = (const float*)d_in[18];
    const float* W_af    = (const float*)d_in[19];
    const float* b_af    = (const float*)d_in[20];
    const float* w_v     = (const float*)d_in[21];
    const float* W_ctx   = (const float*)d_in[22];
    const float* b_ctx   = (const float*)d_in[23];
    const float* dWih    = (const float*)d_in[24];
    const float* dWhh    = (const float*)d_in[25];
    const float* dbih    = (const float*)d_in[26];
    const float* dbhh    = (const float*)d_in[27];
    const float* W_pg    = (const float*)d_in[28];
    const float* b_pg    = (const float*)d_in[29];
    const float* W_o1    = (const float*)d_in[30];
    const float* b_o1    = (const float*)d_in[31];
    const float* W_o2    = (const float*)d_in[32];
    const float* b_o2    = (const float*)d_in[33];

    char* wsb = (char*)d_ws;
    ushort*   emb2d   = (ushort*)(wsb + OFF_EMB2D);
    ushort*   wihcat  = (ushort*)(wsb + OFF_WIHCAT);
    float*    biasx   = (float*)(wsb + OFF_BIASX);
    ushort*   wfeatbf = (ushort*)(wsb + OFF_WFEAT);
    ushort*   wo2bf   = (ushort*)(wsb + OFF_WO2);
    ushort*   wo1T    = (ushort*)(wsb + OFF_WO1T);
    unsigned* whh2    = (unsigned*)(wsb + OFF_WHH2);
    float*    wafT    = (float*)(wsb + OFF_WAFT);
    float*    wrhT    = (float*)(wsb + OFF_WRHT);
    float*    wrcT    = (float*)(wsb + OFF_WRCT);
    float*    wcm     = (float*)(wsb + OFF_WC);
    float*    bcv     = (float*)(wsb + OFF_BC);
    float*    upg     = (float*)(wsb + OFF_UPG);
    float*    cpgp    = (float*)(wsb + OFF_CPG);
    ushort*   xproj   = (ushort*)(wsb + OFF_XPROJ);
    ushort*   encout  = (ushort*)(wsb + OFF_ENCOUT);
    ushort*   encfeat = (ushort*)(wsb + OFF_ENCFEAT);
    float*    hfin    = (float*)(wsb + OFF_HFIN);
    float*    cfin    = (float*)(wsb + OFF_CFIN);
    float*    hdec    = (float*)(wsb + OFF_HDEC);
    float*    cdec    = (float*)(wsb + OFF_CDEC);
    float*    ctx     = (float*)(wsb + OFF_CTX);
    float*    pgen    = (float*)(wsb + OFF_PGEN);
    ushort*   hidbf   = (ushort*)(wsb + OFF_HIDBF);
    float*    pbuf    = (float*)(wsb + OFF_PBUF);

    float* outs = (float*)d_out;
    float* atts = outs + (size_t)T * B * VO;

    int prep_blocks = (int)((PREP_TOTAL + 255) / 256);
    prep_kernel<<<prep_blocks, 256, 0, stream>>>(
        Wih_f, Wih_b, bih_f, bhh_f, bih_b, bhh_b, W_feat, W_o2, W_o1, Whh_f, Whh_b,
        dWih, W_ctx, W_pg, b_pg, b_ctx, dbih, dbhh, emb, inputs, W_af, W_rh, W_rc,
        emb2d, wihcat, biasx, wfeatbf, wo2bf, wo1T, whh2, wcm, upg, cpgp, bcv,
        wafT, wrhT, wrcT);

    // Xproj = emb2d @ [Wih_f; Wih_b]^T + (bih+bhh), f16 output
    gemm_nt<64, 64, 1, true, false><<<dim3(2048 / 64, SB / 64), 256, 0, stream>>>(
        emb2d, 128, wihcat, 128, (void*)xproj, 2048, biasx, SB, 2048, 128);

    enc_kernel<<<64, 512, 0, stream>>>(xproj, (const uint4*)whh2, encout, hfin, cfin);

    initdec_kernel<<<32, 256, 0, stream>>>(hfin, cfin, wrhT, b_rh, wrcT, b_rc, hdec, cdec, ctx);

    // enc_feat = enc_out @ W_feat^T, f16 output
    gemm_nt<64, 64, 1, false, false><<<dim3(512 / 64, SB / 64), 256, 0, stream>>>(
        encout, 512, wfeatbf, 512, (void*)encfeat, 512, nullptr, SB, 512, 512);

    for (int t = 0; t < T; ++t) {
        int in = t & 1, op = in ^ 1;
        float* hin  = hdec + (size_t)in * B * H;
        float* cin  = cdec + (size_t)in * B * H;
        float* hout = hdec + (size_t)op * B * H;
        float* cout = cdec + (size_t)op * B * H;

        dec_lstm_kernel<<<128, 256, 0, stream>>>(ctx, emb, toksAll + t * B, wcm, dWhh, bcv,
                                                 hin, cin, hout, cout);
        dec_attn_kernel<<<32, 512, 0, stream>>>(hout, cout, wafT, b_af, encfeat, w_v,
                                                inputs, encout, ctx, emb, toksAll + t * B,
                                                upg, cpgp, W_pg, wo1T, b_o1, pgen,
                                                atts + (size_t)t * SB, hidbf);
        gemm_nt<32, 128, 2, true, true><<<dim3(391, 1), 256, 0, stream>>>(
            hidbf, 256, wo2bf, 256, (void*)pbuf, V, b_o2, 32, V, 256);
        dec_out_kernel<<<32, 256, 0, stream>>>(pbuf, pgen, tex, atts + (size_t)t * SB,
                                               outs + (size_t)t * B * VO);
    }
}

// Round 3
// 6437.364 us; speedup vs baseline: 1.3551x; 1.2187x over previous
//
#include <hip/hip_runtime.h>

#define DEV static __device__ __forceinline__

typedef short  s16x8 __attribute__((ext_vector_type(8)));
typedef float  f32x4 __attribute__((ext_vector_type(4)));
typedef _Float16 h2f __attribute__((ext_vector_type(2)));

constexpr int S = 400, B = 32, T = 32, V = 50000, OOV = 50, E = 128, H = 256;
constexpr int VO = V + OOV, SB = S * B;
constexpr int VP = 50048;           // fp8 pbuf row stride (64B aligned)

DEV ushort f2bf(float x) {
    union { float f; unsigned u; } a; a.f = x;
    unsigned r = (a.u + 0x7fffu + ((a.u >> 16) & 1u)) >> 16;
    return (ushort)r;
}
DEV float bf2f(unsigned b) {
    union { unsigned u; float f; } a; a.u = b << 16; return a.f;
}
DEV float sigmoidf_(float x) { return 1.0f / (1.0f + __expf(-x)); }
DEV float tanhf_(float x) { float e = __expf(2.0f * x); return 1.0f - 2.0f / (e + 1.0f); }
DEV h2f asH2(unsigned u) { union { unsigned u; h2f h; } x; x.u = u; return x.h; }

#if __has_builtin(__builtin_amdgcn_fdot2)
DEV float dot2(h2f a, h2f b, float c) { return __builtin_amdgcn_fdot2(a, b, c, false); }
#else
DEV float dot2(h2f a, h2f b, float c) { return c + (float)a.x * (float)b.x + (float)a.y * (float)b.y; }
#endif

// fp8 e4m3fn (OCP) manual encode/decode; inputs positive (exp of logits)
DEV unsigned f2e4(float v) {
    union { float f; unsigned u; } a; a.f = v;
    unsigned u = a.u + 0x0007FFFFu + ((a.u >> 20) & 1u);   // RNE to 3 mantissa bits
    int e = (int)((u >> 23) & 255) - 127 + 7;
    unsigned m = (u >> 20) & 7u;
    if (e <= 0) return 0u;
    if (e > 15) { e = 15; m = 6; }
    return (unsigned)((e << 3) | m);
}
DEV float e42f(unsigned b) {
    int e = (int)((b >> 3) & 15), m = (int)(b & 7);
    if (e == 0) return (float)m * 1.953125e-3f;    // subnormal: m * 2^-9
    union { unsigned u; float f; } a;
    a.u = ((unsigned)(e + 120) << 23) | ((unsigned)m << 20);
    return a.f;
}

// ---------------- workspace layout ----------------
constexpr size_t SZ_EMB2D  = (size_t)SB * E * 2;        // bf16
constexpr size_t SZ_WIHCAT = (size_t)2048 * 128 * 2;    // bf16
constexpr size_t SZ_BIASX  = 2048 * 4;
constexpr size_t SZ_WFEAT  = (size_t)512 * 512 * 2;     // bf16
constexpr size_t SZ_WO2    = (size_t)V * H * 2;         // bf16
constexpr size_t SZ_WO1T   = (size_t)1024 * 256 * 2;    // bf16 transposed [k][d]
constexpr size_t SZ_WHH2   = (size_t)2 * 64 * 512 * 16; // f16 packed [dir][chunk][tid]
constexpr size_t SZ_WAFT   = (size_t)512 * 512 * 4;     // f32 transposed [k][d]
constexpr size_t SZ_WRHT   = (size_t)512 * 256 * 4;     // f32 transposed
constexpr size_t SZ_WRCT   = (size_t)512 * 256 * 4;
constexpr size_t SZ_WC     = (size_t)1024 * 640 * 4;
constexpr size_t SZ_BC     = 1024 * 4;
constexpr size_t SZ_UPG    = 640 * 4;
constexpr size_t SZ_CPG    = 256;
constexpr size_t SZ_XPROJ  = (size_t)SB * 2048 * 2;     // f16 (aliased by pbuf later)
constexpr size_t SZ_ENCOUT = (size_t)SB * 512 * 2;      // bf16
constexpr size_t SZ_ENCFEAT= (size_t)SB * 512 * 2;      // f16
constexpr size_t SZ_HFIN   = (size_t)2 * B * H * 4;
constexpr size_t SZ_HDEC   = (size_t)2 * B * H * 4;
constexpr size_t SZ_CTX    = (size_t)B * 512 * 4;
constexpr size_t SZ_PGEN   = (size_t)T * B * 4;
constexpr size_t SZ_HIDALL = (size_t)T * B * 256 * 2;

constexpr size_t OFF_EMB2D  = 0;
constexpr size_t OFF_WIHCAT = OFF_EMB2D  + SZ_EMB2D;
constexpr size_t OFF_BIASX  = OFF_WIHCAT + SZ_WIHCAT;
constexpr size_t OFF_WFEAT  = OFF_BIASX  + SZ_BIASX;
constexpr size_t OFF_WO2    = OFF_WFEAT  + SZ_WFEAT;
constexpr size_t OFF_WO1T   = OFF_WO2    + SZ_WO2;
constexpr size_t OFF_WHH2   = OFF_WO1T   + SZ_WO1T;
constexpr size_t OFF_WAFT   = OFF_WHH2   + SZ_WHH2;
constexpr size_t OFF_WRHT   = OFF_WAFT   + SZ_WAFT;
constexpr size_t OFF_WRCT   = OFF_WRHT   + SZ_WRHT;
constexpr size_t OFF_WC     = OFF_WRCT   + SZ_WRCT;
constexpr size_t OFF_BC     = OFF_WC     + SZ_WC;
constexpr size_t OFF_UPG    = OFF_BC     + SZ_BC;
constexpr size_t OFF_CPG    = OFF_UPG    + SZ_UPG;
constexpr size_t OFF_XPROJ  = OFF_CPG    + SZ_CPG;
constexpr size_t OFF_ENCOUT = OFF_XPROJ  + SZ_XPROJ;
constexpr size_t OFF_ENCFEAT= OFF_ENCOUT + SZ_ENCOUT;
constexpr size_t OFF_HFIN   = OFF_ENCFEAT+ SZ_ENCFEAT;
constexpr size_t OFF_CFIN   = OFF_HFIN   + SZ_HFIN;
constexpr size_t OFF_HDEC   = OFF_CFIN   + SZ_HFIN;
constexpr size_t OFF_CDEC   = OFF_HDEC   + SZ_HDEC;
constexpr size_t OFF_CTX    = OFF_CDEC   + SZ_HDEC;
constexpr size_t OFF_PGEN   = OFF_CTX    + SZ_CTX;
constexpr size_t OFF_HIDALL = OFF_PGEN   + SZ_PGEN;
constexpr size_t OFF_PBUF   = OFF_XPROJ;  // alias: xproj dead after encoder; 1024*VP = 51.2MB < 52.4MB

// ---------------- prep sizes ----------------
constexpr long N1  = 2048L*128;    // wihcat
constexpr long N2  = 2048;         // biasx
constexpr long N3  = 512L*512;     // wfeat
constexpr long N4  = (long)V*H;    // wo2
constexpr long N5  = 1024L*256;    // wo1T (transposed)
constexpr long N6  = 2L*64*512*4;  // whh2 dwords (pair-scheme layout)
constexpr long N7  = 1024L*640;    // wcm
constexpr long N8  = 640;          // upg
constexpr long N9  = 1;            // cpg
constexpr long N10 = 1024;         // bcv
constexpr long N11 = (long)SB*E;   // emb2d
constexpr long N12 = 512L*512;     // wafT
constexpr long N13 = 512L*256;     // wrhT
constexpr long N14 = 512L*256;     // wrcT
constexpr long PREP_TOTAL = N1+N2+N3+N4+N5+N6+N7+N8+N9+N10+N11+N12+N13+N14;

__global__ __launch_bounds__(256)
void prep_kernel(const float* __restrict__ Wih_f, const float* __restrict__ Wih_b,
                 const float* __restrict__ bih_f, const float* __restrict__ bhh_f,
                 const float* __restrict__ bih_b, const float* __restrict__ bhh_b,
                 const float* __restrict__ W_feat, const float* __restrict__ W_o2,
                 const float* __restrict__ W_o1, const float* __restrict__ Whh_f,
                 const float* __restrict__ Whh_b, const float* __restrict__ dWih,
                 const float* __restrict__ W_ctx, const float* __restrict__ W_pg,
                 const float* __restrict__ b_pg, const float* __restrict__ b_ctx,
                 const float* __restrict__ dbih, const float* __restrict__ dbhh,
                 const float* __restrict__ emb, const int* __restrict__ inputs,
                 const float* __restrict__ W_af, const float* __restrict__ W_rh,
                 const float* __restrict__ W_rc,
                 ushort* __restrict__ emb2d, ushort* __restrict__ wihcat,
                 float* __restrict__ biasx, ushort* __restrict__ wfeatbf,
                 ushort* __restrict__ wo2bf, ushort* __restrict__ wo1T,
                 unsigned* __restrict__ whh2, float* __restrict__ wcm,
                 float* __restrict__ upg, float* __restrict__ cpgp, float* __restrict__ bcv,
                 float* __restrict__ wafT, float* __restrict__ wrhT, float* __restrict__ wrcT)
{
    long id = (long)blockIdx.x * 256 + threadIdx.x;
    if (id < N1) { int r = id >> 7, e = id & 127;
        float v = (r < 1024) ? Wih_f[r*128+e] : Wih_b[(r-1024)*128+e];
        wihcat[id] = f2bf(v); return; }
    id -= N1;
    if (id < N2) { biasx[id] = (id < 1024) ? bih_f[id]+bhh_f[id] : bih_b[id-1024]+bhh_b[id-1024]; return; }
    id -= N2;
    if (id < N3) { wfeatbf[id] = f2bf(W_feat[id]); return; }
    id -= N3;
    if (id < N4) { wo2bf[id] = f2bf(W_o2[id]); return; }
    id -= N4;
    if (id < N5) { int d = id & 255; long k = id >> 8;   // wo1T[k][d]
        wo1T[id] = f2bf(W_o1[(size_t)d * 1024 + k]); return; }
    id -= N5;
    if (id < N6) {
        // layout: [dir][c][t] uint4; dword q of chunk c for thread t:
        // gate = c>>4, p = c&15, j = t>>1, kh = t&1, k = kh*128 + p*8 + 2q
        int q = id & 3; long r = id >> 2;
        int t = (int)(r & 511); r >>= 9; int c = (int)(r & 63); int dir = (int)(r >> 6);
        int gate = c >> 4, p = c & 15, j = t >> 1, kh = t & 1;
        int k0 = kh * 128 + p * 8 + 2 * q;
        int row = gate * 256 + j;
        const float* W = dir ? Whh_b : Whh_f;
        h2f hv; hv.x = (_Float16)W[(size_t)row*256 + k0]; hv.y = (_Float16)W[(size_t)row*256 + k0 + 1];
        whh2[id] = __builtin_bit_cast(unsigned, hv); return; }
    id -= N6;
    if (id < N7) { int g = id / 640, u = id % 640;
        float acc = 0.f;
        for (int e = 0; e < 128; ++e) acc += dWih[g*128+e] * W_ctx[e*640+u];
        wcm[id] = acc; return; }
    id -= N7;
    if (id < N8) { float acc = 0.f;
        for (int e = 0; e < 128; ++e) acc += W_pg[1024+e] * W_ctx[e*640+(int)id];
        upg[id] = acc; return; }
    id -= N8;
    if (id < N9) { float acc = b_pg[0];
        for (int e = 0; e < 128; ++e) acc += W_pg[1024+e] * b_ctx[e];
        cpgp[0] = acc; return; }
    id -= N9;
    if (id < N10) { float acc = dbih[id] + dbhh[id];
        for (int e = 0; e < 128; ++e) acc += dWih[id*128+e] * b_ctx[e];
        bcv[id] = acc; return; }
    id -= N10;
    if (id < N11) { long sb = id >> 7; int e = id & 127;
        emb2d[id] = f2bf(emb[(size_t)inputs[sb]*128 + e]); return; }
    id -= N11;
    if (id < N12) { int d = id & 511; long k = id >> 9;  // wafT[k][d]
        wafT[id] = W_af[(size_t)d * 512 + k]; return; }
    id -= N12;
    if (id < N13) { int j = id & 255; long k = id >> 8;  // wrhT[k][j]
        wrhT[id] = W_rh[(size_t)j * 512 + k]; return; }
    id -= N13;
    if (id < N14) { int j = id & 255; long k = id >> 8;
        wrcT[id] = W_rc[(size_t)j * 512 + k]; return; }
}

// ---------------- generic bf16 MFMA GEMM: C = A(MxK) * B(NxK)^T (+bias) ----------------
// MODE: 0 = f32 store, 1 = f16 store, 2 = f32 exp store, 4 = fp8 exp store
template<int BM, int BN, int NT, int MODE, bool BIAS, bool SWZ>
__global__ __launch_bounds__(NT)
void gemm_nt(const ushort* __restrict__ A, int lda, const ushort* __restrict__ Bm, int ldb,
             void* __restrict__ Cp, int ldc, const float* __restrict__ bias,
             int M, int N, int K)
{
    constexpr int WN = BN / 32;
    __shared__ ushort sA[BM * 32];
    __shared__ ushort sB[BN * 32];
    int tid = threadIdx.x, lane = tid & 63, wid = tid >> 6;
    int wm = wid / WN, wn = wid % WN;
    int mb = blockIdx.y, nb = blockIdx.x;
    if (SWZ) {
        int n = gridDim.x, x = nb & 7, y = nb >> 3, q = n >> 3, r = n & 7;
        nb = (x < r ? x * (q + 1) : r * (q + 1) + (x - r) * q) + y;
    }
    int l15 = lane & 15, lg = lane >> 4;
    f32x4 acc[2][2] = {};
    for (int k0 = 0; k0 < K; k0 += 32) {
        for (int idx = tid; idx < BM * 4; idx += NT) {
            int r = idx >> 2, kc = (idx & 3) << 3;
            int row = mb * BM + r;
            uint4 v = make_uint4(0u, 0u, 0u, 0u);
            if (row < M) v = *(const uint4*)(A + (size_t)row * lda + k0 + kc);
            *(uint4*)(&sA[r * 32 + kc]) = v;
        }
        for (int idx = tid; idx < BN * 4; idx += NT) {
            int r = idx >> 2, kc = (idx & 3) << 3;
            int row = nb * BN + r;
            uint4 v = make_uint4(0u, 0u, 0u, 0u);
            if (row < N) v = *(const uint4*)(Bm + (size_t)row * ldb + k0 + kc);
            *(uint4*)(&sB[r * 32 + kc]) = v;
        }
        __syncthreads();
        s16x8 a0 = *(const s16x8*)(&sA[(wm * 32 + l15) * 32 + lg * 8]);
        s16x8 a1 = *(const s16x8*)(&sA[(wm * 32 + 16 + l15) * 32 + lg * 8]);
        s16x8 b0 = *(const s16x8*)(&sB[(wn * 32 + l15) * 32 + lg * 8]);
        s16x8 b1 = *(const s16x8*)(&sB[(wn * 32 + 16 + l15) * 32 + lg * 8]);
        acc[0][0] = __builtin_amdgcn_mfma_f32_16x16x32_bf16(a0, b0, acc[0][0], 0, 0, 0);
        acc[0][1] = __builtin_amdgcn_mfma_f32_16x16x32_bf16(a0, b1, acc[0][1], 0, 0, 0);
        acc[1][0] = __builtin_amdgcn_mfma_f32_16x16x32_bf16(a1, b0, acc[1][0], 0, 0, 0);
        acc[1][1] = __builtin_amdgcn_mfma_f32_16x16x32_bf16(a1, b1, acc[1][1], 0, 0, 0);
        __syncthreads();
    }
    int cb = nb * BN + wn * 32, rb = mb * BM + wm * 32;
    #pragma unroll
    for (int mf = 0; mf < 2; ++mf)
    #pragma unroll
    for (int nf = 0; nf < 2; ++nf) {
        int col = cb + nf * 16 + l15;
        float bv = 0.f;
        if (BIAS) { if (col < N) bv = bias[col]; }
        #pragma unroll
        for (int r = 0; r < 4; ++r) {
            int row = rb + mf * 16 + lg * 4 + r;
            if (row < M && col < N) {
                float v = acc[mf][nf][r] + bv;
                if (MODE == 0)      ((float*)Cp)[(size_t)row * ldc + col] = v;
                else if (MODE == 1) ((ushort*)Cp)[(size_t)row * ldc + col] = __builtin_bit_cast(ushort, (_Float16)v);
                else if (MODE == 2) ((float*)Cp)[(size_t)row * ldc + col] = __expf(v);
                else                ((unsigned char*)Cp)[(size_t)row * ldc + col] = (unsigned char)f2e4(__expf(v));
            }
        }
    }
}

// ---------------- encoder: pair-interleaved persistent kernel ----------------
// 64 WGs (one per dir,b), 512 threads: t -> (j = t>>1, kh = t&1).
// kh-halves of the 4 gates summed via __shfl_xor(.,1); hh double-buffered,
// ONE barrier per step. Weights: 46 uint4 chunks in regs + 18 in LDS.
__global__ __launch_bounds__(512, 2)
void enc_kernel(const ushort* __restrict__ xproj, const uint4* __restrict__ whh2,
                ushort* __restrict__ encout, float* __restrict__ hfin, float* __restrict__ cfin)
{
    __shared__ uint4  wlds[18 * 512];        // 147 KB: g-gate chunks p14,15 + all o-gate
    __shared__ __attribute__((aligned(16))) ushort hh16[2][256];
    int b = blockIdx.x & 31, dir = blockIdx.x >> 5;
    int t = threadIdx.x, j = t >> 1, kh = t & 1;
    const uint4* gw = whh2 + (size_t)dir * 64 * 512 + t;
    uint4 wreg[46];
    #pragma unroll
    for (int c = 0; c < 46; ++c) wreg[c] = gw[(size_t)c * 512];
    #pragma unroll
    for (int c = 46; c < 64; ++c) wlds[(c - 46) * 512 + t] = gw[(size_t)c * 512];
    if (t < 256) { hh16[0][t] = 0; }
    float cst = 0.f, hst = 0.f;
    __syncthreads();
    const int khoff = kh * 512;              // x-load offset
    #pragma unroll 1
    for (int step = 0; step < S; ++step) {
        int s = dir ? (S - 1 - step) : step;
        int cur = step & 1, nxt = cur ^ 1;
        const ushort* xp = xproj + ((size_t)(s * B + b)) * 2048 + dir * 1024 + j + khoff;
        ushort xra = xp[0], xrb = xp[256];   // issued early, consumed after dots
        float a0 = 0.f, a1 = 0.f, a2 = 0.f, a3 = 0.f;
        #pragma unroll
        for (int p = 0; p < 16; ++p) {
            uint4 hp = *(const uint4*)(&hh16[cur][kh * 128 + p * 8]);
            uint4 wi = wreg[p];
            uint4 wf = wreg[16 + p];
            uint4 wg = (p < 14) ? wreg[32 + p] : wlds[(p - 14) * 512 + t];
            uint4 wo = wlds[(p + 2) * 512 + t];
            h2f p0 = asH2(hp.x), p1 = asH2(hp.y), p2 = asH2(hp.z), p3 = asH2(hp.w);
            a0 = dot2(p0, asH2(wi.x), a0); a0 = dot2(p1, asH2(wi.y), a0);
            a0 = dot2(p2, asH2(wi.z), a0); a0 = dot2(p3, asH2(wi.w), a0);
            a1 = dot2(p0, asH2(wf.x), a1); a1 = dot2(p1, asH2(wf.y), a1);
            a1 = dot2(p2, asH2(wf.z), a1); a1 = dot2(p3, asH2(wf.w), a1);
            a2 = dot2(p0, asH2(wg.x), a2); a2 = dot2(p1, asH2(wg.y), a2);
            a2 = dot2(p2, asH2(wg.z), a2); a2 = dot2(p3, asH2(wg.w), a2);
            a3 = dot2(p0, asH2(wo.x), a3); a3 = dot2(p1, asH2(wo.y), a3);
            a3 = dot2(p2, asH2(wo.z), a3); a3 = dot2(p3, asH2(wo.w), a3);
        }
        // add x contributions: even thread holds x_i,x_f; odd holds x_g,x_o
        float xv0 = (float)__builtin_bit_cast(_Float16, xra);
        float xv1 = (float)__builtin_bit_cast(_Float16, xrb);
        a0 += kh ? 0.f : xv0;  a1 += kh ? 0.f : xv1;
        a2 += kh ? xv0 : 0.f;  a3 += kh ? xv1 : 0.f;
        a0 += __shfl_xor(a0, 1); a1 += __shfl_xor(a1, 1);
        a2 += __shfl_xor(a2, 1); a3 += __shfl_xor(a3, 1);
        cst = sigmoidf_(a1) * cst + sigmoidf_(a0) * tanhf_(a2);
        hst = sigmoidf_(a3) * tanhf_(cst);
        if (kh == 0) {
            encout[((size_t)(s * B + b)) * 512 + dir * 256 + j] = f2bf(hst);
            hh16[nxt][j] = __builtin_bit_cast(ushort, (_Float16)hst);
        }
        __syncthreads();
    }
    if (kh == 0) {
        hfin[(dir * 32 + b) * 256 + j] = hst;
        cfin[(dir * 32 + b) * 256 + j] = cst;
    }
}

// ---------------- decoder init ----------------
__global__ __launch_bounds__(256)
void initdec_kernel(const float* __restrict__ hfin, const float* __restrict__ cfin,
                    const float* __restrict__ wrhT, const float* __restrict__ b_rh,
                    const float* __restrict__ wrcT, const float* __restrict__ b_rc,
                    float* __restrict__ hdec0, float* __restrict__ cdec0, float* __restrict__ ctx)
{
    int b = blockIdx.x, j = threadIdx.x;
    float ah = b_rh[j], ac = b_rc[j];
    for (int k = 0; k < 512; ++k) {
        float hv = (k < 256) ? hfin[b * 256 + k] : hfin[(32 + b) * 256 + k - 256];
        float cv = (k < 256) ? cfin[b * 256 + k] : cfin[(32 + b) * 256 + k - 256];
        ah += hv * wrhT[k * 256 + j];
        ac += cv * wrcT[k * 256 + j];
    }
    hdec0[b * 256 + j] = fmaxf(ah, 0.f);
    cdec0[b * 256 + j] = fmaxf(ac, 0.f);
    ctx[b * 512 + j] = 0.f;
    ctx[b * 512 + 256 + j] = 0.f;
}

// ---------------- D1: decoder LSTM ----------------
__global__ __launch_bounds__(256)
void dec_lstm_kernel(const float* __restrict__ ctx, const float* __restrict__ emb,
                     const int* __restrict__ toks, const float* __restrict__ wcm,
                     const float* __restrict__ whh, const float* __restrict__ bcv,
                     const float* __restrict__ hprev, const float* __restrict__ cprev,
                     float* __restrict__ hnew, float* __restrict__ cnew)
{
    int t = threadIdx.x;
    int b = t & 31, ci = t >> 5;
    int gi = ci >> 1, jj = ci & 1;
    int j = (blockIdx.x << 1) + jj;
    int col = gi * 256 + j;
    float acc = bcv[col];
    {
        const float4* w = (const float4*)(wcm + (size_t)col * 640);
        const float4* x = (const float4*)(ctx + b * 512);
        #pragma unroll 8
        for (int u = 0; u < 128; ++u) { float4 a = w[u], q = x[u]; acc += a.x*q.x + a.y*q.y + a.z*q.z + a.w*q.w; }
        const float4* w2 = (const float4*)(wcm + (size_t)col * 640 + 512);
        const float4* x2 = (const float4*)(emb + (size_t)toks[b] * 128);
        #pragma unroll 8
        for (int u = 0; u < 32; ++u) { float4 a = w2[u], q = x2[u]; acc += a.x*q.x + a.y*q.y + a.z*q.z + a.w*q.w; }
        const float4* w3 = (const float4*)(whh + (size_t)col * 256);
        const float4* x3 = (const float4*)(hprev + b * 256);
        #pragma unroll 8
        for (int u = 0; u < 64; ++u) { float4 a = w3[u], q = x3[u]; acc += a.x*q.x + a.y*q.y + a.z*q.z + a.w*q.w; }
    }
    __shared__ float pre[256];
    pre[t] = acc;     // pre[ci*32 + b]
    __syncthreads();
    if (t < 64) {
        int b2 = t & 31, q = t >> 5;
        int j2 = (blockIdx.x << 1) + q;
        float iv = pre[(0 + q) * 32 + b2];
        float fv = pre[(2 + q) * 32 + b2];
        float gv = pre[(4 + q) * 32 + b2];
        float ov = pre[(6 + q) * 32 + b2];
        float cp = cprev[b2 * 256 + j2];
        float cn = sigmoidf_(fv) * cp + sigmoidf_(iv) * tanhf_(gv);
        float hn = sigmoidf_(ov) * tanhf_(cn);
        cnew[b2 * 256 + j2] = cn;
        hnew[b2 * 256 + j2] = hn;
    }
}

// ---------------- D2: fused attention (daf, e, softmax, ctx, pgen, hid) ----------------
// one block per batch row b, 512 threads
__global__ __launch_bounds__(512)
void dec_attn_kernel(const float* __restrict__ h, const float* __restrict__ c,
                     const float* __restrict__ wafT, const float* __restrict__ b_af,
                     const ushort* __restrict__ encfeat, const float* __restrict__ wv,
                     const int* __restrict__ inputs, const ushort* __restrict__ encout,
                     float* __restrict__ ctx, const float* __restrict__ emb,
                     const int* __restrict__ toks, const float* __restrict__ upg,
                     const float* __restrict__ cpgp, const float* __restrict__ wpg,
                     const ushort* __restrict__ wo1T, const float* __restrict__ b_o1,
                     float* __restrict__ pgen, float* __restrict__ attsout,
                     ushort* __restrict__ hidbf)
{
    int b = blockIdx.x, t = threadIdx.x;
    __shared__ float hc[512];
    __shared__ float dafL[8 * 65];
    __shared__ float sc[400];
    __shared__ float red[512];
    __shared__ float ctxL[512];
    // P0: stage [h, c]
    hc[t] = (t < 256) ? h[b * 256 + t] : c[b * 256 + t - 256];
    __syncthreads();
    // P1: daf[d] = b_af[d] + sum_k hc[k] * W_af[d][k]
    {
        float acc = b_af[t];
        #pragma unroll 8
        for (int k = 0; k < 512; ++k) acc += hc[k] * wafT[k * 512 + t];
        dafL[(t >> 6) * 65 + (t & 63)] = acc;
    }
    __syncthreads();
    // P2: e[s] -> exp, masked
    for (int base = 0; base < 400; base += 64) {
        int sloc = base + (t >> 3);
        float p = 0.f;
        if (sloc < 400) {
            int q = t & 7;
            const ushort* ef = encfeat + ((size_t)(sloc * B + b)) * 512 + q * 64;
            const float* dr = dafL + q * 65;
            const float* wr = wv + q * 64;
            #pragma unroll 4
            for (int i = 0; i < 16; ++i) {
                uint2 u = *(const uint2*)(ef + i * 4);
                h2f e0 = asH2(u.x), e1 = asH2(u.y);
                int d = i * 4;
                p += tanhf_((float)e0.x + dr[d + 0]) * wr[d + 0];
                p += tanhf_((float)e0.y + dr[d + 1]) * wr[d + 1];
                p += tanhf_((float)e1.x + dr[d + 2]) * wr[d + 2];
                p += tanhf_((float)e1.y + dr[d + 3]) * wr[d + 3];
            }
        }
        p += __shfl_xor(p, 1);
        p += __shfl_xor(p, 2);
        p += __shfl_xor(p, 4);
        if (sloc < 400 && (t & 7) == 0) {
            float m = (inputs[sloc * B + b] != 0) ? 1.f : 0.f;
            sc[sloc] = m * __expf(p);
        }
    }
    __syncthreads();
    // P3: normalize + write atts
    red[t] = (t < 400) ? sc[t] : 0.f;
    __syncthreads();
    for (int o = 256; o > 0; o >>= 1) { if (t < o) red[t] += red[t + o]; __syncthreads(); }
    float rinv = 1.f / red[0];
    if (t < 400) { float an = sc[t] * rinv; sc[t] = an; attsout[t * 32 + b] = an; }
    __syncthreads();
    // P4: context dim t
    float anew = 0.f;
    {
        const ushort* ebase = encout + (size_t)b * 512 + t;
        #pragma unroll 4
        for (int s = 0; s < 400; ++s) anew += sc[s] * bf2f(ebase[(size_t)s * B * 512]);
    }
    // P5: p_gen partials (reads PREV ctx from global before overwrite)
    {
        float pp = anew * wpg[t] + hc[t] * wpg[512 + t] + ctx[b * 512 + t] * upg[t];
        if (t < 128) pp += emb[(size_t)toks[b] * 128 + t] * upg[512 + t];
        __syncthreads();
        red[t] = pp;
        __syncthreads();
        for (int o = 256; o > 0; o >>= 1) { if (t < o) red[t] += red[t + o]; __syncthreads(); }
        if (t == 0) pgen[b] = sigmoidf_(red[0] + cpgp[0]);
    }
    // P6: commit new ctx
    ctx[b * 512 + t] = anew;
    ctxL[t] = anew;
    __syncthreads();
    // P7: hid[d] = [hc(512), ctx(512)] @ W_o1[d]^T + b_o1[d]; 2 threads per d
    {
        int d = t >> 1, khp = t & 1;
        float acc = 0.f;
        const ushort* wbase = wo1T + (size_t)khp * 512 * 256 + d;
        const float* xs = khp ? ctxL : hc;
        #pragma unroll 8
        for (int k = 0; k < 512; ++k) acc += xs[k] * bf2f(wbase[(size_t)k * 256]);
        acc += __shfl_xor(acc, 1);
        if (khp == 0) hidbf[b * 256 + d] = f2bf(acc + b_o1[d]);
    }
}

// ---------------- D3 (batched): row-sum of fp8 pbuf, scale+write outs, scatter ----------------
// one block per (t,b); blockIdx.x = t*32+b
__global__ __launch_bounds__(256)
void dec_out2_kernel(const unsigned char* __restrict__ pbuf, const float* __restrict__ pgenAll,
                     const int* __restrict__ tex, const float* __restrict__ attsAll,
                     float* __restrict__ outsAll)
{
    int tb = blockIdx.x, t = threadIdx.x;
    int tstep = tb >> 5, b = tb & 31;
    const unsigned char* prow = pbuf + (size_t)tb * VP;
    // pass 1: row sum
    float part = 0.f;
    for (int i = t; i < V / 8; i += 256) {
        uint2 u = *(const uint2*)(prow + i * 8);
        unsigned w0 = u.x, w1 = u.y;
        part += e42f(w0 & 255) + e42f((w0 >> 8) & 255) + e42f((w0 >> 16) & 255) + e42f(w0 >> 24);
        part += e42f(w1 & 255) + e42f((w1 >> 8) & 255) + e42f((w1 >> 16) & 255) + e42f(w1 >> 24);
    }
    __shared__ float red[256];
    red[t] = part;
    __syncthreads();
    for (int o = 128; o > 0; o >>= 1) { if (t < o) red[t] += red[t + o]; __syncthreads(); }
    float pg = pgenAll[tb];
    float sca = pg / red[0];
    float om = 1.f - pg;
    float* orow = outsAll + (size_t)tstep * B * VO + (size_t)b * VO;
    // pass 2: scale + write
    for (int i = t; i < V / 8; i += 256) {
        uint2 u = *(const uint2*)(prow + i * 8);
        unsigned w0 = u.x, w1 = u.y;
        float2* o2 = (float2*)(orow + i * 8);
        o2[0] = make_float2(e42f(w0 & 255) * sca, e42f((w0 >> 8) & 255) * sca);
        o2[1] = make_float2(e42f((w0 >> 16) & 255) * sca, e42f(w0 >> 24) * sca);
        o2[2] = make_float2(e42f(w1 & 255) * sca, e42f((w1 >> 8) & 255) * sca);
        o2[3] = make_float2(e42f((w1 >> 16) & 255) * sca, e42f(w1 >> 24) * sca);
    }
    if (t < OOV) orow[V + t] = 0.f;
    __syncthreads();
    const float* attst = attsAll + (size_t)tstep * SB;
    for (int si = t; si < 400; si += 256)
        atomicAdd(orow + tex[si * 32 + b], om * attst[si * 32 + b]);
}

// ---------------- host ----------------
extern "C" void kernel_launch(void* const* d_in, const int* in_sizes, int n_in,
                              void* d_out, int out_size, void* d_ws, size_t ws_size,
                              hipStream_t stream)
{
    const int*   inputs  = (const int*)d_in[0];
    const int*   toksAll = (const int*)d_in[2];
    const int*   tex     = (const int*)d_in[3];
    const float* emb     = (const float*)d_in[5];
    const float* Wih_f   = (const float*)d_in[6];
    const float* Whh_f   = (const float*)d_in[7];
    const float* bih_f   = (const float*)d_in[8];
    const float* bhh_f   = (const float*)d_in[9];
    const float* Wih_b   = (const float*)d_in[10];
    const float* Whh_b   = (const float*)d_in[11];
    const float* bih_b   = (const float*)d_in[12];
    const float* bhh_b   = (const float*)d_in[13];
    const float* W_feat  = (const float*)d_in[14];
    const float* W_rh    = (const float*)d_in[15];
    const float* b_rh    = (const float*)d_in[16];
    const float* W_rc    = (const float*)d_in[17];
    const float* b_rc    = (const float*)d_in[18];
    const float* W_af    = (const float*)d_in[19];
    const float* b_af    = (const float*)d_in[20];
    const float* w_v     = (const float*)d_in[21];
    const float* W_ctx   = (const float*)d_in[22];
    const float* b_ctx   = (const float*)d_in[23];
    const float* dWih    = (const float*)d_in[24];
    const float* dWhh    = (const float*)d_in[25];
    const float* dbih    = (const float*)d_in[26];
    const float* dbhh    = (const float*)d_in[27];
    const float* W_pg    = (const float*)d_in[28];
    const float* b_pg    = (const float*)d_in[29];
    const float* W_o1    = (const float*)d_in[30];
    const float* b_o1    = (const float*)d_in[31];
    const float* W_o2    = (const float*)d_in[32];
    const float* b_o2    = (const float*)d_in[33];

    char* wsb = (char*)d_ws;
    ushort*   emb2d   = (ushort*)(wsb + OFF_EMB2D);
    ushort*   wihcat  = (ushort*)(wsb + OFF_WIHCAT);
    float*    biasx   = (float*)(wsb + OFF_BIASX);
    ushort*   wfeatbf = (ushort*)(wsb + OFF_WFEAT);
    ushort*   wo2bf   = (ushort*)(wsb + OFF_WO2);
    ushort*   wo1T    = (ushort*)(wsb + OFF_WO1T);
    unsigned* whh2    = (unsigned*)(wsb + OFF_WHH2);
    float*    wafT    = (float*)(wsb + OFF_WAFT);
    float*    wrhT    = (float*)(wsb + OFF_WRHT);
    float*    wrcT    = (float*)(wsb + OFF_WRCT);
    float*    wcm     = (float*)(wsb + OFF_WC);
    float*    bcv     = (float*)(wsb + OFF_BC);
    float*    upg     = (float*)(wsb + OFF_UPG);
    float*    cpgp    = (float*)(wsb + OFF_CPG);
    ushort*   xproj   = (ushort*)(wsb + OFF_XPROJ);
    ushort*   encout  = (ushort*)(wsb + OFF_ENCOUT);
    ushort*   encfeat = (ushort*)(wsb + OFF_ENCFEAT);
    float*    hfin    = (float*)(wsb + OFF_HFIN);
    float*    cfin    = (float*)(wsb + OFF_CFIN);
    float*    hdec    = (float*)(wsb + OFF_HDEC);
    float*    cdec    = (float*)(wsb + OFF_CDEC);
    float*    ctx     = (float*)(wsb + OFF_CTX);
    float*    pgenAll = (float*)(wsb + OFF_PGEN);
    ushort*   hidAll  = (ushort*)(wsb + OFF_HIDALL);
    unsigned char* pbuf = (unsigned char*)(wsb + OFF_PBUF);

    float* outs = (float*)d_out;
    float* atts = outs + (size_t)T * B * VO;

    int prep_blocks = (int)((PREP_TOTAL + 255) / 256);
    prep_kernel<<<prep_blocks, 256, 0, stream>>>(
        Wih_f, Wih_b, bih_f, bhh_f, bih_b, bhh_b, W_feat, W_o2, W_o1, Whh_f, Whh_b,
        dWih, W_ctx, W_pg, b_pg, b_ctx, dbih, dbhh, emb, inputs, W_af, W_rh, W_rc,
        emb2d, wihcat, biasx, wfeatbf, wo2bf, wo1T, whh2, wcm, upg, cpgp, bcv,
        wafT, wrhT, wrcT);

    // Xproj = emb2d @ [Wih_f; Wih_b]^T + (bih+bhh), f16 output
    gemm_nt<64, 64, 256, 1, true, false><<<dim3(2048 / 64, SB / 64), 256, 0, stream>>>(
        emb2d, 128, wihcat, 128, (void*)xproj, 2048, biasx, SB, 2048, 128);

    enc_kernel<<<64, 512, 0, stream>>>(xproj, (const uint4*)whh2, encout, hfin, cfin);

    initdec_kernel<<<32, 256, 0, stream>>>(hfin, cfin, wrhT, b_rh, wrcT, b_rc, hdec, cdec, ctx);

    // enc_feat = enc_out @ W_feat^T, f16 output
    gemm_nt<64, 64, 256, 1, false, false><<<dim3(512 / 64, SB / 64), 256, 0, stream>>>(
        encout, 512, wfeatbf, 512, (void*)encfeat, 512, nullptr, SB, 512, 512);

    for (int t = 0; t < T; ++t) {
        int in = t & 1, op = in ^ 1;
        float* hin  = hdec + (size_t)in * B * H;
        float* cin  = cdec + (size_t)in * B * H;
        float* hout = hdec + (size_t)op * B * H;
        float* cout = cdec + (size_t)op * B * H;

        dec_lstm_kernel<<<128, 256, 0, stream>>>(ctx, emb, toksAll + t * B, wcm, dWhh, bcv,
                                                 hin, cin, hout, cout);
        dec_attn_kernel<<<32, 512, 0, stream>>>(hout, cout, wafT, b_af, encfeat, w_v,
                                                inputs, encout, ctx, emb, toksAll + t * B,
                                                upg, cpgp, W_pg, wo1T, b_o1,
                                                pgenAll + (size_t)t * B,
                                                atts + (size_t)t * SB,
                                                hidAll + (size_t)t * B * 256);
    }
    // batched vocab projection: logits -> exp -> fp8 pbuf
    gemm_nt<64, 128, 512, 4, true, true><<<dim3(391, 16), 512, 0, stream>>>(
        hidAll, 256, wo2bf, 256, (void*)pbuf, VP, b_o2, T * B, V, 256);
    // batched row-sum + scale + write + scatter
    dec_out2_kernel<<<T * B, 256, 0, stream>>>(pbuf, pgenAll, tex, atts, outs);
}